// Round 23
// baseline (384.163 us; speedup 1.0000x reference)
//
#include <hip/hip_runtime.h>

// Problem constants
#define B_   512
#define T_   128
#define D_   384
#define H_   6
#define DH_  64
#define DFF_ 1536
#define NROW (B_*T_)   // 65536 rows

typedef __attribute__((ext_vector_type(8))) short bf16x8;   // MFMA A/B frag (4 VGPRs)
typedef __attribute__((ext_vector_type(4))) float f32x4;    // MFMA C/D frag

__device__ __forceinline__ unsigned short f2bf(float f) {
  union { float f; unsigned u; } v; v.f = f;
  unsigned r = v.u + 0x7fffu + ((v.u >> 16) & 1u);   // RNE
  return (unsigned short)(r >> 16);
}

// lgkm-only barrier (keeps reg-destined global loads in flight)
#define BAR_LGKM() asm volatile("s_waitcnt lgkmcnt(0)\n\ts_barrier" ::: "memory")

// ======== direct fragment-order weight packing from fp32 (R21-proven) ==========
__global__ void pack_wqkv(const float* __restrict__ Wq, const float* __restrict__ Wk,
                          const float* __restrict__ Wv, unsigned short* __restrict__ WP) {
  int tid = blockIdx.x * 256 + threadIdx.x;      // 55296 chunks (216 blocks)
  int lane = tid & 63, frag = tid >> 6;
  int k = frag % 12, t2 = frag / 12;
  int mi = t2 & 1, t3 = t2 >> 1;
  int w = t3 & 3, c = t3 >> 2;                   // c in 0..8
  int l15 = lane & 15, lq = lane >> 4;
  int r = c * 128 + w * 32 + mi * 16 + l15;      // 0..1151
  int col = k * 32 + lq * 8;
  const float* Wsrc = (c < 3) ? Wq : (c < 6) ? Wk : Wv;
  int rr = r - (c / 3) * 384;
  unsigned short tmp[8];
  #pragma unroll
  for (int e = 0; e < 8; ++e)
    tmp[e] = f2bf(Wsrc[(size_t)(col + e) * 384 + rr]);
  *(int4*)(WP + (size_t)tid * 8) = *(const int4*)tmp;
}
__global__ void pack_k384(const float* __restrict__ W, unsigned short* __restrict__ WP,
                          int ld) {
  int tid = blockIdx.x * 256 + threadIdx.x;
  int lane = tid & 63, frag = tid >> 6;
  int k = frag % 12, t2 = frag / 12;
  int mi = t2 & 1, t3 = t2 >> 1;
  int w = t3 & 3, c = t3 >> 2;
  int l15 = lane & 15, lq = lane >> 4;
  int r = c * 128 + w * 32 + mi * 16 + l15;
  int col = k * 32 + lq * 8;
  unsigned short tmp[8];
  #pragma unroll
  for (int e = 0; e < 8; ++e)
    tmp[e] = f2bf(W[(size_t)(col + e) * ld + r]);
  *(int4*)(WP + (size_t)tid * 8) = *(const int4*)tmp;
}
__global__ void pack_w2d(const float* __restrict__ W2, unsigned short* __restrict__ W2P) {
  int tid = blockIdx.x * 256 + threadIdx.x;      // 73728 chunks (288 blocks)
  int lane = tid & 63, frag = tid >> 6;
  int kk = frag & 3, t2 = frag >> 2;
  int c = t2 % 12, t3 = t2 / 12;
  int mi = t3 % 6, w = t3 / 6;
  int l15 = lane & 15, lq = lane >> 4;
  int r = w * 96 + mi * 16 + l15;                // 0..383
  int col = c * 128 + kk * 32 + lq * 8;          // 0..1535
  unsigned short tmp[8];
  #pragma unroll
  for (int e = 0; e < 8; ++e)
    tmp[e] = f2bf(W2[(size_t)(col + e) * 384 + r]);
  *(int4*)(W2P + (size_t)tid * 8) = *(const int4*)tmp;
}

// ---------------- layernorm (LN1): fp32 in -> bf16 out (one wave per row; R9) -------
__global__ __launch_bounds__(256) void ln_kernel(const float* __restrict__ x,
                                                 const float* __restrict__ g,
                                                 const float* __restrict__ be,
                                                 unsigned short* __restrict__ out) {
  int row = (blockIdx.x * 256 + threadIdx.x) >> 6;
  int l = threadIdx.x & 63;
  const float* xr = x + (size_t)row * D_;
  float v[6]; float s = 0.f, ss = 0.f;
  #pragma unroll
  for (int i = 0; i < 6; ++i) { v[i] = xr[l + i*64]; s += v[i]; ss += v[i]*v[i]; }
  #pragma unroll
  for (int m = 1; m < 64; m <<= 1) { s += __shfl_xor(s, m); ss += __shfl_xor(ss, m); }
  float mu  = s * (1.f / D_);
  float var = ss * (1.f / D_) - mu * mu;
  float rs  = rsqrtf(var + 1e-5f);
  unsigned short* orow = out + (size_t)row * D_;
  #pragma unroll
  for (int i = 0; i < 6; ++i) {
    int c = l + i*64;
    orow[c] = f2bf((v[i] - mu) * rs * g[c] + be[c]);
  }
}

// ---------------- QKV GEMM v4 (64-row block, k-outer, deferred epilogue; R22) -------
__global__ __launch_bounds__(512, 2) void qkv_gemm(
    const unsigned short* __restrict__ h, const unsigned short* __restrict__ wP,
    unsigned short* __restrict__ qkv)
{
  __shared__ __align__(16) char smem[49152];   // staging 48KB | epilogue 32x784 reuse
  int tid = threadIdx.x, w = tid >> 6, l = tid & 63;
  int l15 = l & 15, lq = l >> 4;
  size_t R0 = (size_t)blockIdx.x * 64;

  // ---- stage h strip (64 rows) -> frag-order LDS (ffn-proven 512thr x 6 int4) ----
  {
    int row = tid >> 3, gi = row >> 4, l15w = row & 15;
    int cbase = (tid & 7) * 48;
    const unsigned short* src = h + (R0 + row) * 384 + cbase;
    #pragma unroll
    for (int i = 0; i < 6; ++i) {
      int col = cbase + i * 8;
      int k = col >> 5, lqw = (col >> 3) & 3;
      *(int4*)(smem + (gi*12 + k)*1024 + (lqw*16 + l15w)*16) = *(const int4*)(src + i*8);
    }
  }
  __syncthreads();

  f32x4 acc[9][4];
  #pragma unroll
  for (int c = 0; c < 9; ++c)
    #pragma unroll
    for (int ni = 0; ni < 4; ++ni) acc[c][ni] = (f32x4){0.f, 0.f, 0.f, 0.f};

  const unsigned short* wb = wP + l * 8;       // + ((c*8+w)*12 + k)*512

  #define LDG(dst, cb, k)                                                    \
    { _Pragma("unroll") for (int ci = 0; ci < 3; ++ci)                       \
        dst[ci] = *(const bf16x8*)(wb + (((cb)+ci)*8 + w) * 6144 + (k) * 512); }

  #define CMPG(buf, cb)                                                      \
    { _Pragma("unroll") for (int ci = 0; ci < 3; ++ci)                       \
        _Pragma("unroll") for (int ni = 0; ni < 4; ++ni)                     \
          acc[(cb)+ci][ni] = __builtin_amdgcn_mfma_f32_16x16x32_bf16(        \
              buf[ci], bfr[ni], acc[(cb)+ci][ni], 0, 0, 0); }

  bf16x8 a0[3], a1[3], a2[3];
  LDG(a0, 0, 0)                                // preload k=0 group 0

  for (int k = 0; k < 12; ++k) {
    bf16x8 bfr[4];
    #pragma unroll
    for (int ni = 0; ni < 4; ++ni)
      bfr[ni] = *(const bf16x8*)(smem + (ni*12 + k)*1024 + l*16);
    int kn = (k < 11) ? k + 1 : 11;
    LDG(a1, 3, k)
    __builtin_amdgcn_s_setprio(1); CMPG(a0, 0) __builtin_amdgcn_s_setprio(0);
    LDG(a2, 6, k)
    __builtin_amdgcn_s_setprio(1); CMPG(a1, 3) __builtin_amdgcn_s_setprio(0);
    LDG(a0, 0, kn)
    __builtin_amdgcn_s_setprio(1); CMPG(a2, 6) __builtin_amdgcn_s_setprio(0);
  }
  #undef LDG
  #undef CMPG

  // ---- deferred epilogue: per buffer x per 32-row half: acc -> LDS -> int4 stores
  __syncthreads();                              // staging region dead; reads drained
  #pragma unroll
  for (int buf = 0; buf < 3; ++buf) {
    #pragma unroll
    for (int half = 0; half < 2; ++half) {
      #pragma unroll
      for (int ci = 0; ci < 3; ++ci) {
        int c = buf * 3 + ci;
        #pragma unroll
        for (int n2 = 0; n2 < 2; ++n2) {
          int ni = half * 2 + n2;
          int lrow = n2 * 16 + l15;
          ushort4 pk;
          pk.x = f2bf(acc[c][ni][0]);
          pk.y = f2bf(acc[c][ni][1]);
          pk.z = f2bf(acc[c][ni][2]);
          pk.w = f2bf(acc[c][ni][3]);
          *(ushort4*)(smem + lrow * 784 + ci * 256 + w * 32 + lq * 8) = pk;
        }
      }
      __syncthreads();
      {
        int row = tid >> 4;
        unsigned short* obase = qkv + (size_t)buf * NROW * 384
                              + (R0 + half * 32 + row) * 384;
        #pragma unroll
        for (int i = 0; i < 3; ++i) {
          int ob = (tid & 15) * 16 + i * 256;   // byte offset in 768-B row
          *(int4*)(obase + (ob >> 1)) = *(const int4*)(smem + row * 784 + ob);
        }
      }
      __syncthreads();
    }
  }
}

// ---------------- fused Wo + residual + LN2 (32-row block; R19-proven) --------------
__global__ __launch_bounds__(512, 4) void wo_ln(
    const unsigned short* __restrict__ o,    // [NROW][384] bf16 (attention out)
    const unsigned short* __restrict__ wP,   // woP packed (NC=3)
    const float* __restrict__ bo, const float* __restrict__ xres,
    const float* __restrict__ g, const float* __restrict__ be,
    float* __restrict__ x2out,               // d_out
    unsigned short* __restrict__ h2out)      // hb
{
  __shared__ __align__(16) char smem[50176]; // staging 24576 (reused) | x2 tile 32x392 f32
  int tid = threadIdx.x, w = tid >> 6, l = tid & 63;
  int l15 = l & 15, lq = l >> 4;
  size_t R0 = (size_t)blockIdx.x * 32;

  // ---- stage o strip (32 rows) -> frag-order LDS (qkv-v3 pattern) ----
  {
    int row = tid >> 4, gi = row >> 4, l15w = row & 15;
    const unsigned short* src = o + (R0 + row) * 384 + (tid & 15) * 24;
    #pragma unroll
    for (int i = 0; i < 3; ++i) {
      int col = (tid & 15) * 24 + i * 8;
      int k = col >> 5, lqw = (col >> 3) & 3;
      *(int4*)(smem + (gi*12 + k)*1024 + (lqw*16 + l15w)*16) = *(const int4*)(src + i*8);
    }
  }
  __syncthreads();

  f32x4 acc[3][2];
  #pragma unroll
  for (int c = 0; c < 3; ++c)
    #pragma unroll
    for (int ni = 0; ni < 2; ++ni) acc[c][ni] = (f32x4){0.f, 0.f, 0.f, 0.f};

  const unsigned short* wb = wP + l * 8;       // + ((ci*8+w)*12 + k)*512

  #define LDGW(dst, k)                                                       \
    { _Pragma("unroll") for (int ci = 0; ci < 3; ++ci)                       \
        dst[ci] = *(const bf16x8*)(wb + (ci*8 + w) * 6144 + (k) * 512); }

  #define CMPW(buf)                                                          \
    { _Pragma("unroll") for (int ci = 0; ci < 3; ++ci)                       \
        _Pragma("unroll") for (int ni = 0; ni < 2; ++ni)                     \
          acc[ci][ni] = __builtin_amdgcn_mfma_f32_16x16x32_bf16(             \
              buf[ci], bfr[ni], acc[ci][ni], 0, 0, 0); }

  bf16x8 aA[3], aB[3];
  LDGW(aA, 0)
  for (int k = 0; k < 12; k += 2) {
    bf16x8 bfr[2];
    #pragma unroll
    for (int ni = 0; ni < 2; ++ni)
      bfr[ni] = *(const bf16x8*)(smem + (ni*12 + k)*1024 + l*16);
    LDGW(aB, k + 1)
    __builtin_amdgcn_s_setprio(1); CMPW(aA) __builtin_amdgcn_s_setprio(0);
    #pragma unroll
    for (int ni = 0; ni < 2; ++ni)
      bfr[ni] = *(const bf16x8*)(smem + (ni*12 + k + 1)*1024 + l*16);
    int kn = (k + 2 < 12) ? k + 2 : 11;
    LDGW(aA, kn)
    __builtin_amdgcn_s_setprio(1); CMPW(aB) __builtin_amdgcn_s_setprio(0);
  }
  #undef LDGW
  #undef CMPW

  // ---- epilogue: x2 = acc + bo + x -> LDS tile [32][392] f32 ----
  __syncthreads();                              // staging reads retired
  #pragma unroll
  for (int ci = 0; ci < 3; ++ci) {
    int col = ci * 128 + w * 16 + lq * 4;
    float4 bb = *(const float4*)(bo + col);
    #pragma unroll
    for (int ni = 0; ni < 2; ++ni) {
      int row = ni * 16 + l15;
      float4 r = *(const float4*)(xres + (R0 + row) * 384 + col);
      float4 v;
      v.x = acc[ci][ni][0] + bb.x + r.x;
      v.y = acc[ci][ni][1] + bb.y + r.y;
      v.z = acc[ci][ni][2] + bb.z + r.z;
      v.w = acc[ci][ni][3] + bb.w + r.w;
      *(float4*)(smem + row * 1568 + col * 4) = v;
    }
  }
  __syncthreads();

  // ---- LN2 on the tile: 16 thr/row; emit x2 fp32 + h2 bf16 (coalesced) ----
  {
    int row = tid >> 4, t16 = tid & 15;
    const char* rbase = smem + row * 1568;
    float4 vv[6];
    float s = 0.f, ss = 0.f;
    #pragma unroll
    for (int i = 0; i < 6; ++i) {
      vv[i] = *(const float4*)(rbase + (t16 + i * 16) * 16);
      s  += vv[i].x + vv[i].y + vv[i].z + vv[i].w;
      ss += vv[i].x*vv[i].x + vv[i].y*vv[i].y + vv[i].z*vv[i].z + vv[i].w*vv[i].w;
    }
    s += __shfl_xor(s, 1); ss += __shfl_xor(ss, 1);
    s += __shfl_xor(s, 2); ss += __shfl_xor(ss, 2);
    s += __shfl_xor(s, 4); ss += __shfl_xor(ss, 4);
    s += __shfl_xor(s, 8); ss += __shfl_xor(ss, 8);
    float mu = s * (1.f / 384.f);
    float rs = rsqrtf(ss * (1.f / 384.f) - mu * mu + 1e-5f);
    float* xrow = x2out + (R0 + row) * 384;
    unsigned short* hrow = h2out + (R0 + row) * 384;
    #pragma unroll
    for (int i = 0; i < 6; ++i) {
      int c4 = t16 + i * 16;                   // float4 index in row
      float4 ga = *(const float4*)(g  + c4 * 4);
      float4 ba = *(const float4*)(be + c4 * 4);
      *(float4*)(xrow + c4 * 4) = vv[i];
      ushort4 pk;
      pk.x = f2bf((vv[i].x - mu) * rs * ga.x + ba.x);
      pk.y = f2bf((vv[i].y - mu) * rs * ga.y + ba.y);
      pk.z = f2bf((vv[i].z - mu) * rs * ga.z + ba.z);
      pk.w = f2bf((vv[i].w - mu) * rs * ga.w + ba.w);
      *(ushort4*)(hrow + c4 * 4) = pk;
    }
  }
}

// ======== 8-wave ffn building blocks (frag-order LDS + packed W) ========
#define LDA3(dst, pA, k0)                                                    \
  { _Pragma("unroll") for (int kq = 0; kq < 3; ++kq)                         \
      dst[kq] = *(const bf16x8*)((pA) + ((k0) + kq) * 512); }

#define CMP3(buf, k0, acc)                                                   \
  { _Pragma("unroll") for (int kq = 0; kq < 3; ++kq) {                       \
      bf16x8 bfr[4];                                                         \
      _Pragma("unroll") for (int ni = 0; ni < 4; ++ni)                       \
        bfr[ni] = *(const bf16x8*)(smem + (ni*12 + (k0)+kq)*1024 + l*16);    \
      _Pragma("unroll") for (int ni = 0; ni < 4; ++ni)                       \
        acc[ni] = __builtin_amdgcn_mfma_f32_16x16x32_bf16(                   \
            buf[kq], bfr[ni], acc[ni], 0, 0, 0);                             \
    } }

// ---------------- fused FFN (8-wave, setprio, dbuf Psf, 1 barrier/chunk) ------------
// R22 structure + depth-2 prefetch rotation: V-weight loads (kk0,kk1) issued DURING
// the P-phase (in flight across the lgkm-only barrier — they depend on nothing it
// orders); next-chunk A-groups (g0,g1) issued during the PV tail. No sync changes.
__global__ __launch_bounds__(512, 4) void ffn_fused(
    const unsigned short* __restrict__ h2,   // [NROW][384] bf16
    const unsigned short* __restrict__ w1P,  // packed (NC=12)
    const unsigned short* __restrict__ w2P,  // packed (pack_w2d)
    const float* __restrict__ b1,            // [1536]
    const float* __restrict__ b2,            // [384]
    float* __restrict__ out)                 // [NROW][384] fp32, in-place residual add
{
  extern __shared__ __align__(16) char smem[];
  int tid = threadIdx.x, w = tid >> 6, l = tid & 63;
  int l15 = l & 15, lq = l >> 4;
  size_t R0 = (size_t)blockIdx.x * 64;

  // ---- stage h2 strip -> frag-order LDS (512 thr x 48 elems) ----
  {
    int row = tid >> 3, gi = row >> 4, l15w = row & 15;
    int cbase = (tid & 7) * 48;
    const unsigned short* src = h2 + (R0 + row) * 384 + cbase;
    #pragma unroll
    for (int i = 0; i < 6; ++i) {
      int col = cbase + i * 8;
      int k = col >> 5, lqw = (col >> 3) & 3;
      *(int4*)(smem + (gi*12 + k)*1024 + (lqw*16 + l15w)*16) = *(const int4*)(src + i*8);
    }
  }
  __syncthreads();

  f32x4 oacc[3][4];
  #pragma unroll
  for (int i = 0; i < 3; ++i)
    #pragma unroll
    for (int j = 0; j < 4; ++j) oacc[i][j] = (f32x4){0.f, 0.f, 0.f, 0.f};

  const unsigned short* w1b = w1P + w * 6144  + l * 8;  // + c*49152 + k*512
  const unsigned short* w2b = w2P + w * 73728 + l * 8;  // + mi*24576 + c*2048 + kk*512

  #define LDV(dst, pV, kk)                                                   \
    { _Pragma("unroll") for (int mi = 0; mi < 3; ++mi)                       \
        dst[mi] = *(const bf16x8*)((pV) + mi * 24576 + (kk) * 512); }

  #define CMPV(buf, kk, pb)                                                  \
    { bf16x8 bv[4];                                                          \
      _Pragma("unroll") for (int ni = 0; ni < 4; ++ni)                       \
        bv[ni] = *(const bf16x8*)(smem + (pb) + (ni*4 + (kk))*1024 + l*16);  \
      _Pragma("unroll") for (int mi = 0; mi < 3; ++mi)                       \
        _Pragma("unroll") for (int ni = 0; ni < 4; ++ni)                     \
          oacc[mi][ni] = __builtin_amdgcn_mfma_f32_16x16x32_bf16(            \
              buf[mi], bv[ni], oacc[mi][ni], 0, 0, 0);                       \
    }

  bf16x8 af0[3], af1[3], af2[3];
  bf16x8 av0[3], av1[3], av2[3];

  // prologue: g0,g1 of chunk 0 in flight
  LDA3(af0, w1b, 0)
  LDA3(af1, w1b, 3)

  for (int c = 0; c < 12; ++c) {
    const unsigned short* pA  = w1b + (size_t)c * 49152;
    const unsigned short* pAn = w1b + (size_t)(c < 11 ? c + 1 : 11) * 49152;
    const unsigned short* pV  = w2b + c * 2048;
    unsigned pb = 49152u + (unsigned)(c & 1) * 16384u;

    f32x4 pacc[4];
    #pragma unroll
    for (int j = 0; j < 4; ++j) pacc[j] = (f32x4){0.f, 0.f, 0.f, 0.f};

    // P-phase; V-weight loads for kk0/kk1 issued here (cross-barrier flight)
    LDA3(af2, pA, 6)
    __builtin_amdgcn_s_setprio(1); CMP3(af0, 0, pacc) __builtin_amdgcn_s_setprio(0);
    LDA3(af0, pA, 9)
    __builtin_amdgcn_s_setprio(1); CMP3(af1, 3, pacc) __builtin_amdgcn_s_setprio(0);
    LDV(av0, pV, 0)
    __builtin_amdgcn_s_setprio(1); CMP3(af2, 6, pacc) __builtin_amdgcn_s_setprio(0);
    LDV(av1, pV, 1)
    __builtin_amdgcn_s_setprio(1); CMP3(af0, 9, pacc) __builtin_amdgcn_s_setprio(0);

    // P epilogue: bias1 + relu + bf16 pack -> Psf[c&1]  (covers av0/av1 latency)
    {
      int fcb = c * 128 + w * 16 + lq * 4;
      float4 bb = *(const float4*)(b1 + fcb);
      unsigned pw = pb + (unsigned)((w >> 1) * 1024 +
                    (((w & 1) * 2 + (lq >> 1)) * 16 + l15) * 16 + (lq & 1) * 8);
      #pragma unroll
      for (int ni = 0; ni < 4; ++ni) {
        float p0 = pacc[ni][0] + bb.x;
        float p1 = pacc[ni][1] + bb.y;
        float p2 = pacc[ni][2] + bb.z;
        float p3 = pacc[ni][3] + bb.w;
        ushort4 pk;
        pk.x = f2bf(p0 > 0.f ? p0 : 0.f);
        pk.y = f2bf(p1 > 0.f ? p1 : 0.f);
        pk.z = f2bf(p2 > 0.f ? p2 : 0.f);
        pk.w = f2bf(p3 > 0.f ? p3 : 0.f);
        *(ushort4*)(smem + pw + ni * 4096) = pk;
      }
    }
    BAR_LGKM();   // publishes Psf[c&1]; av0/av1 (and all VMEM) stay in flight

    // PV; next chunk's A-groups g0/g1 issued during the tail
    LDV(av2, pV, 2)
    __builtin_amdgcn_s_setprio(1); CMPV(av0, 0, pb) __builtin_amdgcn_s_setprio(0);
    LDV(av0, pV, 3)
    __builtin_amdgcn_s_setprio(1); CMPV(av1, 1, pb) __builtin_amdgcn_s_setprio(0);
    LDA3(af0, pAn, 0)
    __builtin_amdgcn_s_setprio(1); CMPV(av2, 2, pb) __builtin_amdgcn_s_setprio(0);
    LDA3(af1, pAn, 3)
    __builtin_amdgcn_s_setprio(1); CMPV(av0, 3, pb) __builtin_amdgcn_s_setprio(0);
    // no trailing barrier: next chunk writes Psf[(c+1)&1]
  }
  #undef LDV
  #undef CMPV

  // epilogue: out[row][ocol..+3] = oacc + b2 + res  (dwordx4)
  #pragma unroll
  for (int mi = 0; mi < 3; ++mi) {
    int ocb = w * 48 + mi * 16 + lq * 4;
    float4 b2v = *(const float4*)(b2 + ocb);
    #pragma unroll
    for (int ni = 0; ni < 4; ++ni) {
      size_t row = R0 + ni * 16 + l15;
      float* op = out + row * D_ + ocb;
      float4 r = *(const float4*)op;
      float4 o;
      o.x = oacc[mi][ni][0] + b2v.x + r.x;
      o.y = oacc[mi][ni][1] + b2v.y + r.y;
      o.z = oacc[mi][ni][2] + b2v.z + r.z;
      o.w = oacc[mi][ni][3] + b2v.w + r.w;
      *(float4*)op = o;
    }
  }
}

// ---------------- causal attention (+T5 setprio), one block per (b,h) ----------------
__global__ __launch_bounds__(256) void attn_kernel(const unsigned short* __restrict__ q,
                                                   const unsigned short* __restrict__ k,
                                                   const unsigned short* __restrict__ v,
                                                   unsigned short* __restrict__ o) {
  __shared__ __align__(16) char smem[52224];
  unsigned short (*Ks)[72]       = (unsigned short(*)[72])smem;
  unsigned short (*Ps)[32][136]  = (unsigned short(*)[32][136])smem;
  unsigned short (*Vt)[136]      = (unsigned short(*)[136])(smem + 34816);

  int bh = blockIdx.x;
  int b = bh / H_, h = bh % H_;
  int tid = threadIdx.x, w = tid >> 6, l = tid & 63;

  const unsigned short* kb = k + ((size_t)b * T_) * D_ + h * DH_;
  const unsigned short* vb = v + ((size_t)b * T_) * D_ + h * DH_;
  #pragma unroll
  for (int it = 0; it < 4; ++it) {
    int id = it * 256 + tid;
    int s = id >> 3, c8 = (id & 7) * 8;
    int4 kv = *(const int4*)(kb + (size_t)s * D_ + c8);
    *(int4*)(&Ks[s][c8]) = kv;
    int4 vv = *(const int4*)(vb + (size_t)s * D_ + c8);
    const unsigned short* pe = (const unsigned short*)&vv;
    #pragma unroll
    for (int j2 = 0; j2 < 8; ++j2) Vt[c8 + j2][s] = pe[j2];
  }
  __syncthreads();

  const unsigned short* qbp = q + ((size_t)b * T_) * D_ + h * DH_;
  int rowbase = w * 32;
  bf16x8 aq[2][2];
  #pragma unroll
  for (int mi = 0; mi < 2; ++mi)
    #pragma unroll
    for (int ks = 0; ks < 2; ++ks)
      aq[mi][ks] = *(const bf16x8*)(qbp + (size_t)(rowbase + mi*16 + (l & 15)) * D_
                                        + ks*32 + ((l >> 4) << 3));

  f32x4 accs[2][8];
  #pragma unroll
  for (int i = 0; i < 2; ++i)
    #pragma unroll
    for (int j = 0; j < 8; ++j) accs[i][j] = (f32x4){0.f, 0.f, 0.f, 0.f};
  #pragma unroll
  for (int ks = 0; ks < 2; ++ks) {
    bf16x8 bk[8];
    #pragma unroll
    for (int ni = 0; ni < 8; ++ni)
      bk[ni] = *(const bf16x8*)(&Ks[ni*16 + (l & 15)][ks*32 + ((l >> 4) << 3)]);
    __builtin_amdgcn_s_setprio(1);
    #pragma unroll
    for (int mi = 0; mi < 2; ++mi)
      #pragma unroll
      for (int ni = 0; ni < 8; ++ni)
        accs[mi][ni] = __builtin_amdgcn_mfma_f32_16x16x32_bf16(aq[mi][ks], bk[ni], accs[mi][ni], 0, 0, 0);
    __builtin_amdgcn_s_setprio(0);
  }
  __syncthreads();

  #pragma unroll
  for (int mi = 0; mi < 2; ++mi) {
    #pragma unroll
    for (int j = 0; j < 4; ++j) {
      int t = rowbase + mi*16 + ((l >> 4) << 2) + j;
      float mx = -1e30f;
      #pragma unroll
      for (int ni = 0; ni < 8; ++ni) {
        int scol = ni*16 + (l & 15);
        float sv = accs[mi][ni][j] * 0.125f;
        sv = (scol <= t) ? sv : -1e30f;
        accs[mi][ni][j] = sv;
        mx = fmaxf(mx, sv);
      }
      mx = fmaxf(mx, __shfl_xor(mx, 1));
      mx = fmaxf(mx, __shfl_xor(mx, 2));
      mx = fmaxf(mx, __shfl_xor(mx, 4));
      mx = fmaxf(mx, __shfl_xor(mx, 8));
      float sum = 0.f;
      #pragma unroll
      for (int ni = 0; ni < 8; ++ni) {
        float e = __expf(accs[mi][ni][j] - mx);
        accs[mi][ni][j] = e;
        sum += e;
      }
      sum += __shfl_xor(sum, 1);
      sum += __shfl_xor(sum, 2);
      sum += __shfl_xor(sum, 4);
      sum += __shfl_xor(sum, 8);
      float inv = 1.f / sum;
      #pragma unroll
      for (int ni = 0; ni < 8; ++ni)
        Ps[w][mi*16 + ((l >> 4) << 2) + j][ni*16 + (l & 15)] = f2bf(accs[mi][ni][j] * inv);
    }
  }
  __syncthreads();

  f32x4 acco[2][4];
  #pragma unroll
  for (int i = 0; i < 2; ++i)
    #pragma unroll
    for (int j = 0; j < 4; ++j) acco[i][j] = (f32x4){0.f, 0.f, 0.f, 0.f};
  #pragma unroll
  for (int ks = 0; ks < 4; ++ks) {
    bf16x8 ap[2], bv[4];
    #pragma unroll
    for (int mi = 0; mi < 2; ++mi)
      ap[mi] = *(const bf16x8*)(&Ps[w][mi*16 + (l & 15)][ks*32 + ((l >> 4) << 3)]);
    #pragma unroll
    for (int ni = 0; ni < 4; ++ni)
      bv[ni] = *(const bf16x8*)(&Vt[ni*16 + (l & 15)][ks*32 + ((l >> 4) << 3)]);
    __builtin_amdgcn_s_setprio(1);
    #pragma unroll
    for (int mi = 0; mi < 2; ++mi)
      #pragma unroll
      for (int ni = 0; ni < 4; ++ni)
        acco[mi][ni] = __builtin_amdgcn_mfma_f32_16x16x32_bf16(ap[mi], bv[ni], acco[mi][ni], 0, 0, 0);
    __builtin_amdgcn_s_setprio(0);
  }

  unsigned short* ob = o + ((size_t)b * T_) * D_ + h * DH_;
  #pragma unroll
  for (int mi = 0; mi < 2; ++mi)
    #pragma unroll
    for (int ni = 0; ni < 4; ++ni)
      #pragma unroll
      for (int j = 0; j < 4; ++j) {
        int t = rowbase + mi*16 + ((l >> 4) << 2) + j;
        int d = ni*16 + (l & 15);
        ob[(size_t)t * D_ + d] = f2bf(acco[mi][ni][j]);
      }
}

extern "C" void kernel_launch(void* const* d_in, const int* in_sizes, int n_in,
                              void* d_out, int out_size, void* d_ws, size_t ws_size,
                              hipStream_t stream) {
  const float* x   = (const float*)d_in[0];
  const float* Wq  = (const float*)d_in[1];
  const float* Wk  = (const float*)d_in[2];
  const float* Wv  = (const float*)d_in[3];
  const float* Wo  = (const float*)d_in[4];
  const float* bo  = (const float*)d_in[5];
  const float* W1  = (const float*)d_in[6];
  const float* b1  = (const float*)d_in[7];
  const float* W2  = (const float*)d_in[8];
  const float* b2  = (const float*)d_in[9];
  const float* g1  = (const float*)d_in[10];
  const float* be1 = (const float*)d_in[11];
  const float* g2  = (const float*)d_in[12];
  const float* be2 = (const float*)d_in[13];

  // workspace layout (bytes); total ~204 MiB
  char* ws = (char*)d_ws;
  unsigned short* hb    = (unsigned short*)(ws);               // h (LN1), later h2 (LN2)
  unsigned short* qb    = (unsigned short*)(ws +  50331648);   // q|k|v contiguous; o in-place
  unsigned short* kbuf  = (unsigned short*)(ws + 100663296);
  unsigned short* vbuf  = (unsigned short*)(ws + 150994944);
  unsigned short* wqkvP = (unsigned short*)(ws + 201326592);   // packed (pack_wqkv, NC=9)
  unsigned short* woP   = wqkvP + 442368;                      // packed (pack_k384, NC=3)
  unsigned short* w1P   = woP + 147456;                        // packed (pack_k384, NC=12)
  unsigned short* w2P   = w1P + 589824;                        // packed (pack_w2d)
  float* x2 = (float*)d_out;
  (void)kbuf; (void)vbuf;

  // allow 80KB dynamic LDS for ffn_fused (host-side attribute; idempotent)
  hipFuncSetAttribute(reinterpret_cast<const void*>(ffn_fused),
                      hipFuncAttributeMaxDynamicSharedMemorySize, 81920);

  // 1) direct fragment-order packs from fp32 weights (bit-identical values)
  pack_wqkv<<<dim3(216), 256, 0, stream>>>(Wq, Wk, Wv, wqkvP);
  pack_k384<<<dim3(72),  256, 0, stream>>>(Wo, woP, 384);
  pack_k384<<<dim3(288), 256, 0, stream>>>(W1, w1P, 1536);
  pack_w2d <<<dim3(288), 256, 0, stream>>>(W2, w2P);

  // 2) LN1 (R9-exact): x -> h (bf16)
  ln_kernel<<<dim3(NROW / 4), 256, 0, stream>>>(x, g1, be1, hb);

  // 3) QKV GEMM v4 (64-row blocks): q|k|v = h @ [Wq|Wk|Wv]
  qkv_gemm<<<dim3(NROW / 64), 512, 0, stream>>>(hb, wqkvP, qb);

  // 4) attention: o overwrites q in place (per-block disjoint strips)
  attn_kernel<<<dim3(B_ * H_), 256, 0, stream>>>(qb, kbuf, vbuf, qb);

  // 5) fused Wo + residual + LN2: x2 -> d_out (fp32), h2 -> hb (bf16)
  wo_ln<<<dim3(NROW / 32), 512, 0, stream>>>(qb, woP, bo, x, g2, be2, x2, hb);

  // 6) fused FFN (depth-2 prefetch, dbuf-Psf, 1 barrier/chunk, 80KB dyn LDS)
  ffn_fused<<<dim3(NROW / 64), 512, 81920, stream>>>(hb, w1P, w2P, b1, b2, x2);
}

// Round 24
// 381.060 us; speedup vs baseline: 1.0081x; 1.0081x over previous
//
#include <hip/hip_runtime.h>

// Problem constants
#define B_   512
#define T_   128
#define D_   384
#define H_   6
#define DH_  64
#define DFF_ 1536
#define NROW (B_*T_)   // 65536 rows

typedef __attribute__((ext_vector_type(8))) short bf16x8;   // MFMA A/B frag (4 VGPRs)
typedef __attribute__((ext_vector_type(4))) float f32x4;    // MFMA C/D frag

__device__ __forceinline__ unsigned short f2bf(float f) {
  union { float f; unsigned u; } v; v.f = f;
  unsigned r = v.u + 0x7fffu + ((v.u >> 16) & 1u);   // RNE
  return (unsigned short)(r >> 16);
}

// lgkm-only barrier (keeps reg-destined global loads in flight)
#define BAR_LGKM() asm volatile("s_waitcnt lgkmcnt(0)\n\ts_barrier" ::: "memory")

// ======== direct fragment-order weight packing from fp32 (R21-proven) ==========
__global__ void pack_wqkv(const float* __restrict__ Wq, const float* __restrict__ Wk,
                          const float* __restrict__ Wv, unsigned short* __restrict__ WP) {
  int tid = blockIdx.x * 256 + threadIdx.x;      // 55296 chunks (216 blocks)
  int lane = tid & 63, frag = tid >> 6;
  int k = frag % 12, t2 = frag / 12;
  int mi = t2 & 1, t3 = t2 >> 1;
  int w = t3 & 3, c = t3 >> 2;                   // c in 0..8
  int l15 = lane & 15, lq = lane >> 4;
  int r = c * 128 + w * 32 + mi * 16 + l15;      // 0..1151
  int col = k * 32 + lq * 8;
  const float* Wsrc = (c < 3) ? Wq : (c < 6) ? Wk : Wv;
  int rr = r - (c / 3) * 384;
  unsigned short tmp[8];
  #pragma unroll
  for (int e = 0; e < 8; ++e)
    tmp[e] = f2bf(Wsrc[(size_t)(col + e) * 384 + rr]);
  *(int4*)(WP + (size_t)tid * 8) = *(const int4*)tmp;
}
__global__ void pack_k384(const float* __restrict__ W, unsigned short* __restrict__ WP,
                          int ld) {
  int tid = blockIdx.x * 256 + threadIdx.x;
  int lane = tid & 63, frag = tid >> 6;
  int k = frag % 12, t2 = frag / 12;
  int mi = t2 & 1, t3 = t2 >> 1;
  int w = t3 & 3, c = t3 >> 2;
  int l15 = lane & 15, lq = lane >> 4;
  int r = c * 128 + w * 32 + mi * 16 + l15;
  int col = k * 32 + lq * 8;
  unsigned short tmp[8];
  #pragma unroll
  for (int e = 0; e < 8; ++e)
    tmp[e] = f2bf(W[(size_t)(col + e) * ld + r]);
  *(int4*)(WP + (size_t)tid * 8) = *(const int4*)tmp;
}
__global__ void pack_w2d(const float* __restrict__ W2, unsigned short* __restrict__ W2P) {
  int tid = blockIdx.x * 256 + threadIdx.x;      // 73728 chunks (288 blocks)
  int lane = tid & 63, frag = tid >> 6;
  int kk = frag & 3, t2 = frag >> 2;
  int c = t2 % 12, t3 = t2 / 12;
  int mi = t3 % 6, w = t3 / 6;
  int l15 = lane & 15, lq = lane >> 4;
  int r = w * 96 + mi * 16 + l15;                // 0..383
  int col = c * 128 + kk * 32 + lq * 8;          // 0..1535
  unsigned short tmp[8];
  #pragma unroll
  for (int e = 0; e < 8; ++e)
    tmp[e] = f2bf(W2[(size_t)(col + e) * 384 + r]);
  *(int4*)(W2P + (size_t)tid * 8) = *(const int4*)tmp;
}

// ---------------- layernorm (LN1): fp32 in -> bf16 out (one wave per row; R9) -------
__global__ __launch_bounds__(256) void ln_kernel(const float* __restrict__ x,
                                                 const float* __restrict__ g,
                                                 const float* __restrict__ be,
                                                 unsigned short* __restrict__ out) {
  int row = (blockIdx.x * 256 + threadIdx.x) >> 6;
  int l = threadIdx.x & 63;
  const float* xr = x + (size_t)row * D_;
  float v[6]; float s = 0.f, ss = 0.f;
  #pragma unroll
  for (int i = 0; i < 6; ++i) { v[i] = xr[l + i*64]; s += v[i]; ss += v[i]*v[i]; }
  #pragma unroll
  for (int m = 1; m < 64; m <<= 1) { s += __shfl_xor(s, m); ss += __shfl_xor(ss, m); }
  float mu  = s * (1.f / D_);
  float var = ss * (1.f / D_) - mu * mu;
  float rs  = rsqrtf(var + 1e-5f);
  unsigned short* orow = out + (size_t)row * D_;
  #pragma unroll
  for (int i = 0; i < 6; ++i) {
    int c = l + i*64;
    orow[c] = f2bf((v[i] - mu) * rs * g[c] + be[c]);
  }
}

// ---------------- QKV GEMM v4 (64-row block, k-outer, deferred epilogue; R22) -------
__global__ __launch_bounds__(512, 2) void qkv_gemm(
    const unsigned short* __restrict__ h, const unsigned short* __restrict__ wP,
    unsigned short* __restrict__ qkv)
{
  __shared__ __align__(16) char smem[49152];   // staging 48KB | epilogue 32x784 reuse
  int tid = threadIdx.x, w = tid >> 6, l = tid & 63;
  int l15 = l & 15, lq = l >> 4;
  size_t R0 = (size_t)blockIdx.x * 64;

  // ---- stage h strip (64 rows) -> frag-order LDS (ffn-proven 512thr x 6 int4) ----
  {
    int row = tid >> 3, gi = row >> 4, l15w = row & 15;
    int cbase = (tid & 7) * 48;
    const unsigned short* src = h + (R0 + row) * 384 + cbase;
    #pragma unroll
    for (int i = 0; i < 6; ++i) {
      int col = cbase + i * 8;
      int k = col >> 5, lqw = (col >> 3) & 3;
      *(int4*)(smem + (gi*12 + k)*1024 + (lqw*16 + l15w)*16) = *(const int4*)(src + i*8);
    }
  }
  __syncthreads();

  f32x4 acc[9][4];
  #pragma unroll
  for (int c = 0; c < 9; ++c)
    #pragma unroll
    for (int ni = 0; ni < 4; ++ni) acc[c][ni] = (f32x4){0.f, 0.f, 0.f, 0.f};

  const unsigned short* wb = wP + l * 8;       // + ((c*8+w)*12 + k)*512

  #define LDG(dst, cb, k)                                                    \
    { _Pragma("unroll") for (int ci = 0; ci < 3; ++ci)                       \
        dst[ci] = *(const bf16x8*)(wb + (((cb)+ci)*8 + w) * 6144 + (k) * 512); }

  #define CMPG(buf, cb)                                                      \
    { _Pragma("unroll") for (int ci = 0; ci < 3; ++ci)                       \
        _Pragma("unroll") for (int ni = 0; ni < 4; ++ni)                     \
          acc[(cb)+ci][ni] = __builtin_amdgcn_mfma_f32_16x16x32_bf16(        \
              buf[ci], bfr[ni], acc[(cb)+ci][ni], 0, 0, 0); }

  bf16x8 a0[3], a1[3], a2[3];
  LDG(a0, 0, 0)                                // preload k=0 group 0

  for (int k = 0; k < 12; ++k) {
    bf16x8 bfr[4];
    #pragma unroll
    for (int ni = 0; ni < 4; ++ni)
      bfr[ni] = *(const bf16x8*)(smem + (ni*12 + k)*1024 + l*16);
    int kn = (k < 11) ? k + 1 : 11;
    LDG(a1, 3, k)
    __builtin_amdgcn_s_setprio(1); CMPG(a0, 0) __builtin_amdgcn_s_setprio(0);
    LDG(a2, 6, k)
    __builtin_amdgcn_s_setprio(1); CMPG(a1, 3) __builtin_amdgcn_s_setprio(0);
    LDG(a0, 0, kn)
    __builtin_amdgcn_s_setprio(1); CMPG(a2, 6) __builtin_amdgcn_s_setprio(0);
  }
  #undef LDG
  #undef CMPG

  // ---- deferred epilogue: per buffer x per 32-row half: acc -> LDS -> int4 stores
  __syncthreads();                              // staging region dead; reads drained
  #pragma unroll
  for (int buf = 0; buf < 3; ++buf) {
    #pragma unroll
    for (int half = 0; half < 2; ++half) {
      #pragma unroll
      for (int ci = 0; ci < 3; ++ci) {
        int c = buf * 3 + ci;
        #pragma unroll
        for (int n2 = 0; n2 < 2; ++n2) {
          int ni = half * 2 + n2;
          int lrow = n2 * 16 + l15;
          ushort4 pk;
          pk.x = f2bf(acc[c][ni][0]);
          pk.y = f2bf(acc[c][ni][1]);
          pk.z = f2bf(acc[c][ni][2]);
          pk.w = f2bf(acc[c][ni][3]);
          *(ushort4*)(smem + lrow * 784 + ci * 256 + w * 32 + lq * 8) = pk;
        }
      }
      __syncthreads();
      {
        int row = tid >> 4;
        unsigned short* obase = qkv + (size_t)buf * NROW * 384
                              + (R0 + half * 32 + row) * 384;
        #pragma unroll
        for (int i = 0; i < 3; ++i) {
          int ob = (tid & 15) * 16 + i * 256;   // byte offset in 768-B row
          *(int4*)(obase + (ob >> 1)) = *(const int4*)(smem + row * 784 + ob);
        }
      }
      __syncthreads();
    }
  }
}

// ---------------- fused Wo + residual + LN2 (32-row block; R19-proven) --------------
__global__ __launch_bounds__(512, 4) void wo_ln(
    const unsigned short* __restrict__ o,    // [NROW][384] bf16 (attention out)
    const unsigned short* __restrict__ wP,   // woP packed (NC=3)
    const float* __restrict__ bo, const float* __restrict__ xres,
    const float* __restrict__ g, const float* __restrict__ be,
    float* __restrict__ x2out,               // d_out
    unsigned short* __restrict__ h2out)      // hb
{
  __shared__ __align__(16) char smem[50176]; // staging 24576 (reused) | x2 tile 32x392 f32
  int tid = threadIdx.x, w = tid >> 6, l = tid & 63;
  int l15 = l & 15, lq = l >> 4;
  size_t R0 = (size_t)blockIdx.x * 32;

  // ---- stage o strip (32 rows) -> frag-order LDS (qkv-v3 pattern) ----
  {
    int row = tid >> 4, gi = row >> 4, l15w = row & 15;
    const unsigned short* src = o + (R0 + row) * 384 + (tid & 15) * 24;
    #pragma unroll
    for (int i = 0; i < 3; ++i) {
      int col = (tid & 15) * 24 + i * 8;
      int k = col >> 5, lqw = (col >> 3) & 3;
      *(int4*)(smem + (gi*12 + k)*1024 + (lqw*16 + l15w)*16) = *(const int4*)(src + i*8);
    }
  }
  __syncthreads();

  f32x4 acc[3][2];
  #pragma unroll
  for (int c = 0; c < 3; ++c)
    #pragma unroll
    for (int ni = 0; ni < 2; ++ni) acc[c][ni] = (f32x4){0.f, 0.f, 0.f, 0.f};

  const unsigned short* wb = wP + l * 8;       // + ((ci*8+w)*12 + k)*512

  #define LDGW(dst, k)                                                       \
    { _Pragma("unroll") for (int ci = 0; ci < 3; ++ci)                       \
        dst[ci] = *(const bf16x8*)(wb + (ci*8 + w) * 6144 + (k) * 512); }

  #define CMPW(buf)                                                          \
    { _Pragma("unroll") for (int ci = 0; ci < 3; ++ci)                       \
        _Pragma("unroll") for (int ni = 0; ni < 2; ++ni)                     \
          acc[ci][ni] = __builtin_amdgcn_mfma_f32_16x16x32_bf16(             \
              buf[ci], bfr[ni], acc[ci][ni], 0, 0, 0); }

  bf16x8 aA[3], aB[3];
  LDGW(aA, 0)
  for (int k = 0; k < 12; k += 2) {
    bf16x8 bfr[2];
    #pragma unroll
    for (int ni = 0; ni < 2; ++ni)
      bfr[ni] = *(const bf16x8*)(smem + (ni*12 + k)*1024 + l*16);
    LDGW(aB, k + 1)
    __builtin_amdgcn_s_setprio(1); CMPW(aA) __builtin_amdgcn_s_setprio(0);
    #pragma unroll
    for (int ni = 0; ni < 2; ++ni)
      bfr[ni] = *(const bf16x8*)(smem + (ni*12 + k + 1)*1024 + l*16);
    int kn = (k + 2 < 12) ? k + 2 : 11;
    LDGW(aA, kn)
    __builtin_amdgcn_s_setprio(1); CMPW(aB) __builtin_amdgcn_s_setprio(0);
  }
  #undef LDGW
  #undef CMPW

  // ---- epilogue: x2 = acc + bo + x -> LDS tile [32][392] f32 ----
  __syncthreads();                              // staging reads retired
  #pragma unroll
  for (int ci = 0; ci < 3; ++ci) {
    int col = ci * 128 + w * 16 + lq * 4;
    float4 bb = *(const float4*)(bo + col);
    #pragma unroll
    for (int ni = 0; ni < 2; ++ni) {
      int row = ni * 16 + l15;
      float4 r = *(const float4*)(xres + (R0 + row) * 384 + col);
      float4 v;
      v.x = acc[ci][ni][0] + bb.x + r.x;
      v.y = acc[ci][ni][1] + bb.y + r.y;
      v.z = acc[ci][ni][2] + bb.z + r.z;
      v.w = acc[ci][ni][3] + bb.w + r.w;
      *(float4*)(smem + row * 1568 + col * 4) = v;
    }
  }
  __syncthreads();

  // ---- LN2 on the tile: 16 thr/row; emit x2 fp32 + h2 bf16 (coalesced) ----
  {
    int row = tid >> 4, t16 = tid & 15;
    const char* rbase = smem + row * 1568;
    float4 vv[6];
    float s = 0.f, ss = 0.f;
    #pragma unroll
    for (int i = 0; i < 6; ++i) {
      vv[i] = *(const float4*)(rbase + (t16 + i * 16) * 16);
      s  += vv[i].x + vv[i].y + vv[i].z + vv[i].w;
      ss += vv[i].x*vv[i].x + vv[i].y*vv[i].y + vv[i].z*vv[i].z + vv[i].w*vv[i].w;
    }
    s += __shfl_xor(s, 1); ss += __shfl_xor(ss, 1);
    s += __shfl_xor(s, 2); ss += __shfl_xor(ss, 2);
    s += __shfl_xor(s, 4); ss += __shfl_xor(ss, 4);
    s += __shfl_xor(s, 8); ss += __shfl_xor(ss, 8);
    float mu = s * (1.f / 384.f);
    float rs = rsqrtf(ss * (1.f / 384.f) - mu * mu + 1e-5f);
    float* xrow = x2out + (R0 + row) * 384;
    unsigned short* hrow = h2out + (R0 + row) * 384;
    #pragma unroll
    for (int i = 0; i < 6; ++i) {
      int c4 = t16 + i * 16;                   // float4 index in row
      float4 ga = *(const float4*)(g  + c4 * 4);
      float4 ba = *(const float4*)(be + c4 * 4);
      *(float4*)(xrow + c4 * 4) = vv[i];
      ushort4 pk;
      pk.x = f2bf((vv[i].x - mu) * rs * ga.x + ba.x);
      pk.y = f2bf((vv[i].y - mu) * rs * ga.y + ba.y);
      pk.z = f2bf((vv[i].z - mu) * rs * ga.z + ba.z);
      pk.w = f2bf((vv[i].w - mu) * rs * ga.w + ba.w);
      *(ushort4*)(hrow + c4 * 4) = pk;
    }
  }
}

// ======== 8-wave ffn building blocks (frag-order LDS + packed W) ========
#define LDA3(dst, pA, k0)                                                    \
  { _Pragma("unroll") for (int kq = 0; kq < 3; ++kq)                         \
      dst[kq] = *(const bf16x8*)((pA) + ((k0) + kq) * 512); }

#define CMP3(buf, k0, acc)                                                   \
  { _Pragma("unroll") for (int kq = 0; kq < 3; ++kq) {                       \
      bf16x8 bfr[4];                                                         \
      _Pragma("unroll") for (int ni = 0; ni < 4; ++ni)                       \
        bfr[ni] = *(const bf16x8*)(smem + (ni*12 + (k0)+kq)*1024 + l*16);    \
      _Pragma("unroll") for (int ni = 0; ni < 4; ++ni)                       \
        acc[ni] = __builtin_amdgcn_mfma_f32_16x16x32_bf16(                   \
            buf[kq], bfr[ni], acc[ni], 0, 0, 0);                             \
    } }

// ---------------- fused FFN (8-wave, setprio, dbuf Psf, 1 barrier/chunk; R22-exact) -
__global__ __launch_bounds__(512, 4) void ffn_fused(
    const unsigned short* __restrict__ h2,   // [NROW][384] bf16
    const unsigned short* __restrict__ w1P,  // packed (NC=12)
    const unsigned short* __restrict__ w2P,  // packed (pack_w2d)
    const float* __restrict__ b1,            // [1536]
    const float* __restrict__ b2,            // [384]
    float* __restrict__ out)                 // [NROW][384] fp32, in-place residual add
{
  extern __shared__ __align__(16) char smem[];
  int tid = threadIdx.x, w = tid >> 6, l = tid & 63;
  int l15 = l & 15, lq = l >> 4;
  size_t R0 = (size_t)blockIdx.x * 64;

  // ---- stage h2 strip -> frag-order LDS (512 thr x 48 elems) ----
  {
    int row = tid >> 3, gi = row >> 4, l15w = row & 15;
    int cbase = (tid & 7) * 48;
    const unsigned short* src = h2 + (R0 + row) * 384 + cbase;
    #pragma unroll
    for (int i = 0; i < 6; ++i) {
      int col = cbase + i * 8;
      int k = col >> 5, lqw = (col >> 3) & 3;
      *(int4*)(smem + (gi*12 + k)*1024 + (lqw*16 + l15w)*16) = *(const int4*)(src + i*8);
    }
  }
  __syncthreads();

  f32x4 oacc[3][4];
  #pragma unroll
  for (int i = 0; i < 3; ++i)
    #pragma unroll
    for (int j = 0; j < 4; ++j) oacc[i][j] = (f32x4){0.f, 0.f, 0.f, 0.f};

  const unsigned short* w1b = w1P + w * 6144  + l * 8;  // + c*49152 + k*512
  const unsigned short* w2b = w2P + w * 73728 + l * 8;  // + mi*24576 + c*2048 + kk*512

  #define LDV(dst, pV, kk)                                                   \
    { _Pragma("unroll") for (int mi = 0; mi < 3; ++mi)                       \
        dst[mi] = *(const bf16x8*)((pV) + mi * 24576 + (kk) * 512); }

  #define CMPV(buf, kk, pb)                                                  \
    { bf16x8 bv[4];                                                          \
      _Pragma("unroll") for (int ni = 0; ni < 4; ++ni)                       \
        bv[ni] = *(const bf16x8*)(smem + (pb) + (ni*4 + (kk))*1024 + l*16);  \
      _Pragma("unroll") for (int mi = 0; mi < 3; ++mi)                       \
        _Pragma("unroll") for (int ni = 0; ni < 4; ++ni)                     \
          oacc[mi][ni] = __builtin_amdgcn_mfma_f32_16x16x32_bf16(            \
              buf[mi], bv[ni], oacc[mi][ni], 0, 0, 0);                       \
    }

  bf16x8 afA[3], afB[3];
  bf16x8 avA[3], avB[3];

  LDA3(afA, w1b, 0)   // prologue: first P-group of chunk 0

  for (int c = 0; c < 12; ++c) {
    const unsigned short* pA = w1b + (size_t)c * 49152;
    const unsigned short* pV = w2b + c * 2048;
    unsigned pb = 49152u + (unsigned)(c & 1) * 16384u;

    f32x4 pacc[4];
    #pragma unroll
    for (int j = 0; j < 4; ++j) pacc[j] = (f32x4){0.f, 0.f, 0.f, 0.f};

    // P-phase: 4 groups of 3 k-steps, ping-pong prefetch; T5 around MFMA clusters
    LDA3(afB, pA, 3)
    __builtin_amdgcn_s_setprio(1); CMP3(afA, 0, pacc) __builtin_amdgcn_s_setprio(0);
    LDA3(afA, pA, 6)
    __builtin_amdgcn_s_setprio(1); CMP3(afB, 3, pacc) __builtin_amdgcn_s_setprio(0);
    LDA3(afB, pA, 9)
    __builtin_amdgcn_s_setprio(1); CMP3(afA, 6, pacc) __builtin_amdgcn_s_setprio(0);
    LDV(avA, pV, 0)
    __builtin_amdgcn_s_setprio(1); CMP3(afB, 9, pacc) __builtin_amdgcn_s_setprio(0);

    // P epilogue: bias1 + relu + bf16 pack -> Psf[c&1]
    {
      int fcb = c * 128 + w * 16 + lq * 4;
      float4 bb = *(const float4*)(b1 + fcb);
      unsigned pw = pb + (unsigned)((w >> 1) * 1024 +
                    (((w & 1) * 2 + (lq >> 1)) * 16 + l15) * 16 + (lq & 1) * 8);
      #pragma unroll
      for (int ni = 0; ni < 4; ++ni) {
        float p0 = pacc[ni][0] + bb.x;
        float p1 = pacc[ni][1] + bb.y;
        float p2 = pacc[ni][2] + bb.z;
        float p3 = pacc[ni][3] + bb.w;
        ushort4 pk;
        pk.x = f2bf(p0 > 0.f ? p0 : 0.f);
        pk.y = f2bf(p1 > 0.f ? p1 : 0.f);
        pk.z = f2bf(p2 > 0.f ? p2 : 0.f);
        pk.w = f2bf(p3 > 0.f ? p3 : 0.f);
        *(ushort4*)(smem + pw + ni * 4096) = pk;
      }
    }
    BAR_LGKM();   // single barrier per chunk: Psf[c&1] visible; prefetches in flight

    const unsigned short* pAn = w1b + (size_t)(c < 11 ? c + 1 : 11) * 49152;
    LDV(avB, pV, 1)
    __builtin_amdgcn_s_setprio(1); CMPV(avA, 0, pb) __builtin_amdgcn_s_setprio(0);
    LDV(avA, pV, 2)
    __builtin_amdgcn_s_setprio(1); CMPV(avB, 1, pb) __builtin_amdgcn_s_setprio(0);
    LDV(avB, pV, 3)
    __builtin_amdgcn_s_setprio(1); CMPV(avA, 2, pb) __builtin_amdgcn_s_setprio(0);
    LDA3(afA, pAn, 0)
    __builtin_amdgcn_s_setprio(1); CMPV(avB, 3, pb) __builtin_amdgcn_s_setprio(0);
    // no trailing barrier: next chunk writes Psf[(c+1)&1]
  }
  #undef LDV
  #undef CMPV

  // epilogue: out[row][ocol..+3] = oacc + b2 + res  (dwordx4)
  #pragma unroll
  for (int mi = 0; mi < 3; ++mi) {
    int ocb = w * 48 + mi * 16 + lq * 4;
    float4 b2v = *(const float4*)(b2 + ocb);
    #pragma unroll
    for (int ni = 0; ni < 4; ++ni) {
      size_t row = R0 + ni * 16 + l15;
      float* op = out + row * D_ + ocb;
      float4 r = *(const float4*)op;
      float4 o;
      o.x = oacc[mi][ni][0] + b2v.x + r.x;
      o.y = oacc[mi][ni][1] + b2v.y + r.y;
      o.z = oacc[mi][ni][2] + b2v.z + r.z;
      o.w = oacc[mi][ni][3] + b2v.w + r.w;
      *(float4*)op = o;
    }
  }
}

// ---------------- causal attention (+T5 setprio), one block per (b,h) ----------------
__global__ __launch_bounds__(256) void attn_kernel(const unsigned short* __restrict__ q,
                                                   const unsigned short* __restrict__ k,
                                                   const unsigned short* __restrict__ v,
                                                   unsigned short* __restrict__ o) {
  __shared__ __align__(16) char smem[52224];
  unsigned short (*Ks)[72]       = (unsigned short(*)[72])smem;
  unsigned short (*Ps)[32][136]  = (unsigned short(*)[32][136])smem;
  unsigned short (*Vt)[136]      = (unsigned short(*)[136])(smem + 34816);

  int bh = blockIdx.x;
  int b = bh / H_, h = bh % H_;
  int tid = threadIdx.x, w = tid >> 6, l = tid & 63;

  const unsigned short* kb = k + ((size_t)b * T_) * D_ + h * DH_;
  const unsigned short* vb = v + ((size_t)b * T_) * D_ + h * DH_;
  #pragma unroll
  for (int it = 0; it < 4; ++it) {
    int id = it * 256 + tid;
    int s = id >> 3, c8 = (id & 7) * 8;
    int4 kv = *(const int4*)(kb + (size_t)s * D_ + c8);
    *(int4*)(&Ks[s][c8]) = kv;
    int4 vv = *(const int4*)(vb + (size_t)s * D_ + c8);
    const unsigned short* pe = (const unsigned short*)&vv;
    #pragma unroll
    for (int j2 = 0; j2 < 8; ++j2) Vt[c8 + j2][s] = pe[j2];
  }
  __syncthreads();

  const unsigned short* qbp = q + ((size_t)b * T_) * D_ + h * DH_;
  int rowbase = w * 32;
  bf16x8 aq[2][2];
  #pragma unroll
  for (int mi = 0; mi < 2; ++mi)
    #pragma unroll
    for (int ks = 0; ks < 2; ++ks)
      aq[mi][ks] = *(const bf16x8*)(qbp + (size_t)(rowbase + mi*16 + (l & 15)) * D_
                                        + ks*32 + ((l >> 4) << 3));

  f32x4 accs[2][8];
  #pragma unroll
  for (int i = 0; i < 2; ++i)
    #pragma unroll
    for (int j = 0; j < 8; ++j) accs[i][j] = (f32x4){0.f, 0.f, 0.f, 0.f};
  #pragma unroll
  for (int ks = 0; ks < 2; ++ks) {
    bf16x8 bk[8];
    #pragma unroll
    for (int ni = 0; ni < 8; ++ni)
      bk[ni] = *(const bf16x8*)(&Ks[ni*16 + (l & 15)][ks*32 + ((l >> 4) << 3)]);
    __builtin_amdgcn_s_setprio(1);
    #pragma unroll
    for (int mi = 0; mi < 2; ++mi)
      #pragma unroll
      for (int ni = 0; ni < 8; ++ni)
        accs[mi][ni] = __builtin_amdgcn_mfma_f32_16x16x32_bf16(aq[mi][ks], bk[ni], accs[mi][ni], 0, 0, 0);
    __builtin_amdgcn_s_setprio(0);
  }
  __syncthreads();

  #pragma unroll
  for (int mi = 0; mi < 2; ++mi) {
    #pragma unroll
    for (int j = 0; j < 4; ++j) {
      int t = rowbase + mi*16 + ((l >> 4) << 2) + j;
      float mx = -1e30f;
      #pragma unroll
      for (int ni = 0; ni < 8; ++ni) {
        int scol = ni*16 + (l & 15);
        float sv = accs[mi][ni][j] * 0.125f;
        sv = (scol <= t) ? sv : -1e30f;
        accs[mi][ni][j] = sv;
        mx = fmaxf(mx, sv);
      }
      mx = fmaxf(mx, __shfl_xor(mx, 1));
      mx = fmaxf(mx, __shfl_xor(mx, 2));
      mx = fmaxf(mx, __shfl_xor(mx, 4));
      mx = fmaxf(mx, __shfl_xor(mx, 8));
      float sum = 0.f;
      #pragma unroll
      for (int ni = 0; ni < 8; ++ni) {
        float e = __expf(accs[mi][ni][j] - mx);
        accs[mi][ni][j] = e;
        sum += e;
      }
      sum += __shfl_xor(sum, 1);
      sum += __shfl_xor(sum, 2);
      sum += __shfl_xor(sum, 4);
      sum += __shfl_xor(sum, 8);
      float inv = 1.f / sum;
      #pragma unroll
      for (int ni = 0; ni < 8; ++ni)
        Ps[w][mi*16 + ((l >> 4) << 2) + j][ni*16 + (l & 15)] = f2bf(accs[mi][ni][j] * inv);
    }
  }
  __syncthreads();

  f32x4 acco[2][4];
  #pragma unroll
  for (int i = 0; i < 2; ++i)
    #pragma unroll
    for (int j = 0; j < 4; ++j) acco[i][j] = (f32x4){0.f, 0.f, 0.f, 0.f};
  #pragma unroll
  for (int ks = 0; ks < 4; ++ks) {
    bf16x8 ap[2], bv[4];
    #pragma unroll
    for (int mi = 0; mi < 2; ++mi)
      ap[mi] = *(const bf16x8*)(&Ps[w][mi*16 + (l & 15)][ks*32 + ((l >> 4) << 3)]);
    #pragma unroll
    for (int ni = 0; ni < 4; ++ni)
      bv[ni] = *(const bf16x8*)(&Vt[ni*16 + (l & 15)][ks*32 + ((l >> 4) << 3)]);
    __builtin_amdgcn_s_setprio(1);
    #pragma unroll
    for (int mi = 0; mi < 2; ++mi)
      #pragma unroll
      for (int ni = 0; ni < 4; ++ni)
        acco[mi][ni] = __builtin_amdgcn_mfma_f32_16x16x32_bf16(ap[mi], bv[ni], acco[mi][ni], 0, 0, 0);
    __builtin_amdgcn_s_setprio(0);
  }

  unsigned short* ob = o + ((size_t)b * T_) * D_ + h * DH_;
  #pragma unroll
  for (int mi = 0; mi < 2; ++mi)
    #pragma unroll
    for (int ni = 0; ni < 4; ++ni)
      #pragma unroll
      for (int j = 0; j < 4; ++j) {
        int t = rowbase + mi*16 + ((l >> 4) << 2) + j;
        int d = ni*16 + (l & 15);
        ob[(size_t)t * D_ + d] = f2bf(acco[mi][ni][j]);
      }
}

extern "C" void kernel_launch(void* const* d_in, const int* in_sizes, int n_in,
                              void* d_out, int out_size, void* d_ws, size_t ws_size,
                              hipStream_t stream) {
  const float* x   = (const float*)d_in[0];
  const float* Wq  = (const float*)d_in[1];
  const float* Wk  = (const float*)d_in[2];
  const float* Wv  = (const float*)d_in[3];
  const float* Wo  = (const float*)d_in[4];
  const float* bo  = (const float*)d_in[5];
  const float* W1  = (const float*)d_in[6];
  const float* b1  = (const float*)d_in[7];
  const float* W2  = (const float*)d_in[8];
  const float* b2  = (const float*)d_in[9];
  const float* g1  = (const float*)d_in[10];
  const float* be1 = (const float*)d_in[11];
  const float* g2  = (const float*)d_in[12];
  const float* be2 = (const float*)d_in[13];

  // workspace layout (bytes); total ~204 MiB
  char* ws = (char*)d_ws;
  unsigned short* hb    = (unsigned short*)(ws);               // h (LN1), later h2 (LN2)
  unsigned short* qb    = (unsigned short*)(ws +  50331648);   // q|k|v contiguous; o in-place
  unsigned short* kbuf  = (unsigned short*)(ws + 100663296);
  unsigned short* vbuf  = (unsigned short*)(ws + 150994944);
  unsigned short* wqkvP = (unsigned short*)(ws + 201326592);   // packed (pack_wqkv, NC=9)
  unsigned short* woP   = wqkvP + 442368;                      // packed (pack_k384, NC=3)
  unsigned short* w1P   = woP + 147456;                        // packed (pack_k384, NC=12)
  unsigned short* w2P   = w1P + 589824;                        // packed (pack_w2d)
  float* x2 = (float*)d_out;
  (void)kbuf; (void)vbuf;

  // allow 80KB dynamic LDS for ffn_fused (host-side attribute; idempotent)
  hipFuncSetAttribute(reinterpret_cast<const void*>(ffn_fused),
                      hipFuncAttributeMaxDynamicSharedMemorySize, 81920);

  // 1) direct fragment-order packs from fp32 weights (bit-identical values)
  pack_wqkv<<<dim3(216), 256, 0, stream>>>(Wq, Wk, Wv, wqkvP);
  pack_k384<<<dim3(72),  256, 0, stream>>>(Wo, woP, 384);
  pack_k384<<<dim3(288), 256, 0, stream>>>(W1, w1P, 1536);
  pack_w2d <<<dim3(288), 256, 0, stream>>>(W2, w2P);

  // 2) LN1 (R9-exact): x -> h (bf16)
  ln_kernel<<<dim3(NROW / 4), 256, 0, stream>>>(x, g1, be1, hb);

  // 3) QKV GEMM v4 (64-row blocks): q|k|v = h @ [Wq|Wk|Wv]
  qkv_gemm<<<dim3(NROW / 64), 512, 0, stream>>>(hb, wqkvP, qb);

  // 4) attention: o overwrites q in place (per-block disjoint strips)
  attn_kernel<<<dim3(B_ * H_), 256, 0, stream>>>(qb, kbuf, vbuf, qb);

  // 5) fused Wo + residual + LN2: x2 -> d_out (fp32), h2 -> hb (bf16)
  wo_ln<<<dim3(NROW / 32), 512, 0, stream>>>(qb, woP, bo, x, g2, be2, x2, hb);

  // 6) fused FFN (dbuf-Psf, 1 barrier/chunk, 80KB dyn LDS; R22-exact)
  ffn_fused<<<dim3(NROW / 64), 512, 81920, stream>>>(hb, w1P, w2P, b1, b2, x2);
}

// Round 25
// 376.717 us; speedup vs baseline: 1.0198x; 1.0115x over previous
//
#include <hip/hip_runtime.h>

// Problem constants
#define B_   512
#define T_   128
#define D_   384
#define H_   6
#define DH_  64
#define DFF_ 1536
#define NROW (B_*T_)   // 65536 rows

typedef __attribute__((ext_vector_type(8))) short bf16x8;   // MFMA A/B frag (4 VGPRs)
typedef __attribute__((ext_vector_type(4))) float f32x4;    // MFMA C/D frag

__device__ __forceinline__ unsigned short f2bf(float f) {
  union { float f; unsigned u; } v; v.f = f;
  unsigned r = v.u + 0x7fffu + ((v.u >> 16) & 1u);   // RNE
  return (unsigned short)(r >> 16);
}

// lgkm-only barrier (keeps reg-destined global loads in flight)
#define BAR_LGKM() asm volatile("s_waitcnt lgkmcnt(0)\n\ts_barrier" ::: "memory")

// ======== unified fragment-order weight pack (one dispatch; bit-identical values) ====
// blocks [0,216): wqkv | [216,288): wo | [288,576): w1 | [576,864): w2
__global__ void pack_all(const float* __restrict__ Wq, const float* __restrict__ Wk,
                         const float* __restrict__ Wv, const float* __restrict__ Wo,
                         const float* __restrict__ W1, const float* __restrict__ W2,
                         unsigned short* __restrict__ wqkvP,
                         unsigned short* __restrict__ woP,
                         unsigned short* __restrict__ w1P,
                         unsigned short* __restrict__ w2P) {
  int blk = blockIdx.x;
  if (blk < 216) {                                  // ---- wqkv (NC=9, K=384) ----
    int tid = blk * 256 + threadIdx.x;
    int lane = tid & 63, frag = tid >> 6;
    int k = frag % 12, t2 = frag / 12;
    int mi = t2 & 1, t3 = t2 >> 1;
    int w = t3 & 3, c = t3 >> 2;
    int l15 = lane & 15, lq = lane >> 4;
    int r = c * 128 + w * 32 + mi * 16 + l15;
    int col = k * 32 + lq * 8;
    const float* Wsrc = (c < 3) ? Wq : (c < 6) ? Wk : Wv;
    int rr = r - (c / 3) * 384;
    unsigned short tmp[8];
    #pragma unroll
    for (int e = 0; e < 8; ++e)
      tmp[e] = f2bf(Wsrc[(size_t)(col + e) * 384 + rr]);
    *(int4*)(wqkvP + (size_t)tid * 8) = *(const int4*)tmp;
  } else if (blk < 288) {                           // ---- wo (NC=3, K=384) ----
    int tid = (blk - 216) * 256 + threadIdx.x;
    int lane = tid & 63, frag = tid >> 6;
    int k = frag % 12, t2 = frag / 12;
    int mi = t2 & 1, t3 = t2 >> 1;
    int w = t3 & 3, c = t3 >> 2;
    int l15 = lane & 15, lq = lane >> 4;
    int r = c * 128 + w * 32 + mi * 16 + l15;
    int col = k * 32 + lq * 8;
    unsigned short tmp[8];
    #pragma unroll
    for (int e = 0; e < 8; ++e)
      tmp[e] = f2bf(Wo[(size_t)(col + e) * 384 + r]);
    *(int4*)(woP + (size_t)tid * 8) = *(const int4*)tmp;
  } else if (blk < 576) {                           // ---- w1 (NC=12, K=384, ld=1536) -
    int tid = (blk - 288) * 256 + threadIdx.x;
    int lane = tid & 63, frag = tid >> 6;
    int k = frag % 12, t2 = frag / 12;
    int mi = t2 & 1, t3 = t2 >> 1;
    int w = t3 & 3, c = t3 >> 2;
    int l15 = lane & 15, lq = lane >> 4;
    int r = c * 128 + w * 32 + mi * 16 + l15;
    int col = k * 32 + lq * 8;
    unsigned short tmp[8];
    #pragma unroll
    for (int e = 0; e < 8; ++e)
      tmp[e] = f2bf(W1[(size_t)(col + e) * 1536 + r]);
    *(int4*)(w1P + (size_t)tid * 8) = *(const int4*)tmp;
  } else {                                          // ---- w2 (K=1536) ----
    int tid = (blk - 576) * 256 + threadIdx.x;
    int lane = tid & 63, frag = tid >> 6;
    int kk = frag & 3, t2 = frag >> 2;
    int c = t2 % 12, t3 = t2 / 12;
    int mi = t3 % 6, w = t3 / 6;
    int l15 = lane & 15, lq = lane >> 4;
    int r = w * 96 + mi * 16 + l15;
    int col = c * 128 + kk * 32 + lq * 8;
    unsigned short tmp[8];
    #pragma unroll
    for (int e = 0; e < 8; ++e)
      tmp[e] = f2bf(W2[(size_t)(col + e) * 384 + r]);
    *(int4*)(w2P + (size_t)tid * 8) = *(const int4*)tmp;
  }
}

// ---------------- layernorm (LN1): grid-stride, one wave per row (math R9-exact) ----
__global__ __launch_bounds__(256) void ln_kernel(const float* __restrict__ x,
                                                 const float* __restrict__ g,
                                                 const float* __restrict__ be,
                                                 unsigned short* __restrict__ out) {
  int l = threadIdx.x & 63;
  int wid0 = (blockIdx.x * 256 + threadIdx.x) >> 6;   // global wave id
  int nw = gridDim.x * 4;                              // waves per grid pass
  for (int row = wid0; row < NROW; row += nw) {
    const float* xr = x + (size_t)row * D_;
    float v[6]; float s = 0.f, ss = 0.f;
    #pragma unroll
    for (int i = 0; i < 6; ++i) { v[i] = xr[l + i*64]; s += v[i]; ss += v[i]*v[i]; }
    #pragma unroll
    for (int m = 1; m < 64; m <<= 1) { s += __shfl_xor(s, m); ss += __shfl_xor(ss, m); }
    float mu  = s * (1.f / D_);
    float var = ss * (1.f / D_) - mu * mu;
    float rs  = rsqrtf(var + 1e-5f);
    unsigned short* orow = out + (size_t)row * D_;
    #pragma unroll
    for (int i = 0; i < 6; ++i) {
      int c = l + i*64;
      orow[c] = f2bf((v[i] - mu) * rs * g[c] + be[c]);
    }
  }
}

// ---------------- QKV GEMM v4 (64-row block, k-outer, deferred epilogue; R22) -------
__global__ __launch_bounds__(512, 2) void qkv_gemm(
    const unsigned short* __restrict__ h, const unsigned short* __restrict__ wP,
    unsigned short* __restrict__ qkv)
{
  __shared__ __align__(16) char smem[49152];   // staging 48KB | epilogue 32x784 reuse
  int tid = threadIdx.x, w = tid >> 6, l = tid & 63;
  int l15 = l & 15, lq = l >> 4;
  size_t R0 = (size_t)blockIdx.x * 64;

  // ---- stage h strip (64 rows) -> frag-order LDS (ffn-proven 512thr x 6 int4) ----
  {
    int row = tid >> 3, gi = row >> 4, l15w = row & 15;
    int cbase = (tid & 7) * 48;
    const unsigned short* src = h + (R0 + row) * 384 + cbase;
    #pragma unroll
    for (int i = 0; i < 6; ++i) {
      int col = cbase + i * 8;
      int k = col >> 5, lqw = (col >> 3) & 3;
      *(int4*)(smem + (gi*12 + k)*1024 + (lqw*16 + l15w)*16) = *(const int4*)(src + i*8);
    }
  }
  __syncthreads();

  f32x4 acc[9][4];
  #pragma unroll
  for (int c = 0; c < 9; ++c)
    #pragma unroll
    for (int ni = 0; ni < 4; ++ni) acc[c][ni] = (f32x4){0.f, 0.f, 0.f, 0.f};

  const unsigned short* wb = wP + l * 8;       // + ((c*8+w)*12 + k)*512

  #define LDG(dst, cb, k)                                                    \
    { _Pragma("unroll") for (int ci = 0; ci < 3; ++ci)                       \
        dst[ci] = *(const bf16x8*)(wb + (((cb)+ci)*8 + w) * 6144 + (k) * 512); }

  #define CMPG(buf, cb)                                                      \
    { _Pragma("unroll") for (int ci = 0; ci < 3; ++ci)                       \
        _Pragma("unroll") for (int ni = 0; ni < 4; ++ni)                     \
          acc[(cb)+ci][ni] = __builtin_amdgcn_mfma_f32_16x16x32_bf16(        \
              buf[ci], bfr[ni], acc[(cb)+ci][ni], 0, 0, 0); }

  bf16x8 a0[3], a1[3], a2[3];
  LDG(a0, 0, 0)                                // preload k=0 group 0

  for (int k = 0; k < 12; ++k) {
    bf16x8 bfr[4];
    #pragma unroll
    for (int ni = 0; ni < 4; ++ni)
      bfr[ni] = *(const bf16x8*)(smem + (ni*12 + k)*1024 + l*16);
    int kn = (k < 11) ? k + 1 : 11;
    LDG(a1, 3, k)
    __builtin_amdgcn_s_setprio(1); CMPG(a0, 0) __builtin_amdgcn_s_setprio(0);
    LDG(a2, 6, k)
    __builtin_amdgcn_s_setprio(1); CMPG(a1, 3) __builtin_amdgcn_s_setprio(0);
    LDG(a0, 0, kn)
    __builtin_amdgcn_s_setprio(1); CMPG(a2, 6) __builtin_amdgcn_s_setprio(0);
  }
  #undef LDG
  #undef CMPG

  // ---- deferred epilogue: per buffer x per 32-row half: acc -> LDS -> int4 stores
  __syncthreads();                              // staging region dead; reads drained
  #pragma unroll
  for (int buf = 0; buf < 3; ++buf) {
    #pragma unroll
    for (int half = 0; half < 2; ++half) {
      #pragma unroll
      for (int ci = 0; ci < 3; ++ci) {
        int c = buf * 3 + ci;
        #pragma unroll
        for (int n2 = 0; n2 < 2; ++n2) {
          int ni = half * 2 + n2;
          int lrow = n2 * 16 + l15;
          ushort4 pk;
          pk.x = f2bf(acc[c][ni][0]);
          pk.y = f2bf(acc[c][ni][1]);
          pk.z = f2bf(acc[c][ni][2]);
          pk.w = f2bf(acc[c][ni][3]);
          *(ushort4*)(smem + lrow * 784 + ci * 256 + w * 32 + lq * 8) = pk;
        }
      }
      __syncthreads();
      {
        int row = tid >> 4;
        unsigned short* obase = qkv + (size_t)buf * NROW * 384
                              + (R0 + half * 32 + row) * 384;
        #pragma unroll
        for (int i = 0; i < 3; ++i) {
          int ob = (tid & 15) * 16 + i * 256;   // byte offset in 768-B row
          *(int4*)(obase + (ob >> 1)) = *(const int4*)(smem + row * 784 + ob);
        }
      }
      __syncthreads();
    }
  }
}

// ---------------- fused Wo + residual + LN2 (32-row block; R19-proven) --------------
__global__ __launch_bounds__(512, 4) void wo_ln(
    const unsigned short* __restrict__ o,    // [NROW][384] bf16 (attention out)
    const unsigned short* __restrict__ wP,   // woP packed (NC=3)
    const float* __restrict__ bo, const float* __restrict__ xres,
    const float* __restrict__ g, const float* __restrict__ be,
    float* __restrict__ x2out,               // d_out
    unsigned short* __restrict__ h2out)      // hb
{
  __shared__ __align__(16) char smem[50176]; // staging 24576 (reused) | x2 tile 32x392 f32
  int tid = threadIdx.x, w = tid >> 6, l = tid & 63;
  int l15 = l & 15, lq = l >> 4;
  size_t R0 = (size_t)blockIdx.x * 32;

  // ---- stage o strip (32 rows) -> frag-order LDS (qkv-v3 pattern) ----
  {
    int row = tid >> 4, gi = row >> 4, l15w = row & 15;
    const unsigned short* src = o + (R0 + row) * 384 + (tid & 15) * 24;
    #pragma unroll
    for (int i = 0; i < 3; ++i) {
      int col = (tid & 15) * 24 + i * 8;
      int k = col >> 5, lqw = (col >> 3) & 3;
      *(int4*)(smem + (gi*12 + k)*1024 + (lqw*16 + l15w)*16) = *(const int4*)(src + i*8);
    }
  }
  __syncthreads();

  f32x4 acc[3][2];
  #pragma unroll
  for (int c = 0; c < 3; ++c)
    #pragma unroll
    for (int ni = 0; ni < 2; ++ni) acc[c][ni] = (f32x4){0.f, 0.f, 0.f, 0.f};

  const unsigned short* wb = wP + l * 8;       // + ((ci*8+w)*12 + k)*512

  #define LDGW(dst, k)                                                       \
    { _Pragma("unroll") for (int ci = 0; ci < 3; ++ci)                       \
        dst[ci] = *(const bf16x8*)(wb + (ci*8 + w) * 6144 + (k) * 512); }

  #define CMPW(buf)                                                          \
    { _Pragma("unroll") for (int ci = 0; ci < 3; ++ci)                       \
        _Pragma("unroll") for (int ni = 0; ni < 2; ++ni)                     \
          acc[ci][ni] = __builtin_amdgcn_mfma_f32_16x16x32_bf16(             \
              buf[ci], bfr[ni], acc[ci][ni], 0, 0, 0); }

  bf16x8 aA[3], aB[3];
  LDGW(aA, 0)
  for (int k = 0; k < 12; k += 2) {
    bf16x8 bfr[2];
    #pragma unroll
    for (int ni = 0; ni < 2; ++ni)
      bfr[ni] = *(const bf16x8*)(smem + (ni*12 + k)*1024 + l*16);
    LDGW(aB, k + 1)
    __builtin_amdgcn_s_setprio(1); CMPW(aA) __builtin_amdgcn_s_setprio(0);
    #pragma unroll
    for (int ni = 0; ni < 2; ++ni)
      bfr[ni] = *(const bf16x8*)(smem + (ni*12 + k + 1)*1024 + l*16);
    int kn = (k + 2 < 12) ? k + 2 : 11;
    LDGW(aA, kn)
    __builtin_amdgcn_s_setprio(1); CMPW(aB) __builtin_amdgcn_s_setprio(0);
  }
  #undef LDGW
  #undef CMPW

  // ---- epilogue: x2 = acc + bo + x -> LDS tile [32][392] f32 ----
  __syncthreads();                              // staging reads retired
  #pragma unroll
  for (int ci = 0; ci < 3; ++ci) {
    int col = ci * 128 + w * 16 + lq * 4;
    float4 bb = *(const float4*)(bo + col);
    #pragma unroll
    for (int ni = 0; ni < 2; ++ni) {
      int row = ni * 16 + l15;
      float4 r = *(const float4*)(xres + (R0 + row) * 384 + col);
      float4 v;
      v.x = acc[ci][ni][0] + bb.x + r.x;
      v.y = acc[ci][ni][1] + bb.y + r.y;
      v.z = acc[ci][ni][2] + bb.z + r.z;
      v.w = acc[ci][ni][3] + bb.w + r.w;
      *(float4*)(smem + row * 1568 + col * 4) = v;
    }
  }
  __syncthreads();

  // ---- LN2 on the tile: 16 thr/row; emit x2 fp32 + h2 bf16 (coalesced) ----
  {
    int row = tid >> 4, t16 = tid & 15;
    const char* rbase = smem + row * 1568;
    float4 vv[6];
    float s = 0.f, ss = 0.f;
    #pragma unroll
    for (int i = 0; i < 6; ++i) {
      vv[i] = *(const float4*)(rbase + (t16 + i * 16) * 16);
      s  += vv[i].x + vv[i].y + vv[i].z + vv[i].w;
      ss += vv[i].x*vv[i].x + vv[i].y*vv[i].y + vv[i].z*vv[i].z + vv[i].w*vv[i].w;
    }
    s += __shfl_xor(s, 1); ss += __shfl_xor(ss, 1);
    s += __shfl_xor(s, 2); ss += __shfl_xor(ss, 2);
    s += __shfl_xor(s, 4); ss += __shfl_xor(ss, 4);
    s += __shfl_xor(s, 8); ss += __shfl_xor(ss, 8);
    float mu = s * (1.f / 384.f);
    float rs = rsqrtf(ss * (1.f / 384.f) - mu * mu + 1e-5f);
    float* xrow = x2out + (R0 + row) * 384;
    unsigned short* hrow = h2out + (R0 + row) * 384;
    #pragma unroll
    for (int i = 0; i < 6; ++i) {
      int c4 = t16 + i * 16;                   // float4 index in row
      float4 ga = *(const float4*)(g  + c4 * 4);
      float4 ba = *(const float4*)(be + c4 * 4);
      *(float4*)(xrow + c4 * 4) = vv[i];
      ushort4 pk;
      pk.x = f2bf((vv[i].x - mu) * rs * ga.x + ba.x);
      pk.y = f2bf((vv[i].y - mu) * rs * ga.y + ba.y);
      pk.z = f2bf((vv[i].z - mu) * rs * ga.z + ba.z);
      pk.w = f2bf((vv[i].w - mu) * rs * ga.w + ba.w);
      *(ushort4*)(hrow + c4 * 4) = pk;
    }
  }
}

// ======== 8-wave ffn building blocks (frag-order LDS + packed W) ========
#define LDA3(dst, pA, k0)                                                    \
  { _Pragma("unroll") for (int kq = 0; kq < 3; ++kq)                         \
      dst[kq] = *(const bf16x8*)((pA) + ((k0) + kq) * 512); }

#define CMP3(buf, k0, acc)                                                   \
  { _Pragma("unroll") for (int kq = 0; kq < 3; ++kq) {                       \
      bf16x8 bfr[4];                                                         \
      _Pragma("unroll") for (int ni = 0; ni < 4; ++ni)                       \
        bfr[ni] = *(const bf16x8*)(smem + (ni*12 + (k0)+kq)*1024 + l*16);    \
      _Pragma("unroll") for (int ni = 0; ni < 4; ++ni)                       \
        acc[ni] = __builtin_amdgcn_mfma_f32_16x16x32_bf16(                   \
            buf[kq], bfr[ni], acc[ni], 0, 0, 0);                             \
    } }

// ---------------- fused FFN (8-wave, setprio, dbuf Psf, 1 barrier/chunk; R22-exact) -
__global__ __launch_bounds__(512, 4) void ffn_fused(
    const unsigned short* __restrict__ h2,   // [NROW][384] bf16
    const unsigned short* __restrict__ w1P,  // packed (NC=12)
    const unsigned short* __restrict__ w2P,  // packed (pack_w2d)
    const float* __restrict__ b1,            // [1536]
    const float* __restrict__ b2,            // [384]
    float* __restrict__ out)                 // [NROW][384] fp32, in-place residual add
{
  extern __shared__ __align__(16) char smem[];
  int tid = threadIdx.x, w = tid >> 6, l = tid & 63;
  int l15 = l & 15, lq = l >> 4;
  size_t R0 = (size_t)blockIdx.x * 64;

  // ---- stage h2 strip -> frag-order LDS (512 thr x 48 elems) ----
  {
    int row = tid >> 3, gi = row >> 4, l15w = row & 15;
    int cbase = (tid & 7) * 48;
    const unsigned short* src = h2 + (R0 + row) * 384 + cbase;
    #pragma unroll
    for (int i = 0; i < 6; ++i) {
      int col = cbase + i * 8;
      int k = col >> 5, lqw = (col >> 3) & 3;
      *(int4*)(smem + (gi*12 + k)*1024 + (lqw*16 + l15w)*16) = *(const int4*)(src + i*8);
    }
  }
  __syncthreads();

  f32x4 oacc[3][4];
  #pragma unroll
  for (int i = 0; i < 3; ++i)
    #pragma unroll
    for (int j = 0; j < 4; ++j) oacc[i][j] = (f32x4){0.f, 0.f, 0.f, 0.f};

  const unsigned short* w1b = w1P + w * 6144  + l * 8;  // + c*49152 + k*512
  const unsigned short* w2b = w2P + w * 73728 + l * 8;  // + mi*24576 + c*2048 + kk*512

  #define LDV(dst, pV, kk)                                                   \
    { _Pragma("unroll") for (int mi = 0; mi < 3; ++mi)                       \
        dst[mi] = *(const bf16x8*)((pV) + mi * 24576 + (kk) * 512); }

  #define CMPV(buf, kk, pb)                                                  \
    { bf16x8 bv[4];                                                          \
      _Pragma("unroll") for (int ni = 0; ni < 4; ++ni)                       \
        bv[ni] = *(const bf16x8*)(smem + (pb) + (ni*4 + (kk))*1024 + l*16);  \
      _Pragma("unroll") for (int mi = 0; mi < 3; ++mi)                       \
        _Pragma("unroll") for (int ni = 0; ni < 4; ++ni)                     \
          oacc[mi][ni] = __builtin_amdgcn_mfma_f32_16x16x32_bf16(            \
              buf[mi], bv[ni], oacc[mi][ni], 0, 0, 0);                       \
    }

  bf16x8 afA[3], afB[3];
  bf16x8 avA[3], avB[3];

  LDA3(afA, w1b, 0)   // prologue: first P-group of chunk 0

  for (int c = 0; c < 12; ++c) {
    const unsigned short* pA = w1b + (size_t)c * 49152;
    const unsigned short* pV = w2b + c * 2048;
    unsigned pb = 49152u + (unsigned)(c & 1) * 16384u;

    f32x4 pacc[4];
    #pragma unroll
    for (int j = 0; j < 4; ++j) pacc[j] = (f32x4){0.f, 0.f, 0.f, 0.f};

    // P-phase: 4 groups of 3 k-steps, ping-pong prefetch; T5 around MFMA clusters
    LDA3(afB, pA, 3)
    __builtin_amdgcn_s_setprio(1); CMP3(afA, 0, pacc) __builtin_amdgcn_s_setprio(0);
    LDA3(afA, pA, 6)
    __builtin_amdgcn_s_setprio(1); CMP3(afB, 3, pacc) __builtin_amdgcn_s_setprio(0);
    LDA3(afB, pA, 9)
    __builtin_amdgcn_s_setprio(1); CMP3(afA, 6, pacc) __builtin_amdgcn_s_setprio(0);
    LDV(avA, pV, 0)
    __builtin_amdgcn_s_setprio(1); CMP3(afB, 9, pacc) __builtin_amdgcn_s_setprio(0);

    // P epilogue: bias1 + relu + bf16 pack -> Psf[c&1]
    {
      int fcb = c * 128 + w * 16 + lq * 4;
      float4 bb = *(const float4*)(b1 + fcb);
      unsigned pw = pb + (unsigned)((w >> 1) * 1024 +
                    (((w & 1) * 2 + (lq >> 1)) * 16 + l15) * 16 + (lq & 1) * 8);
      #pragma unroll
      for (int ni = 0; ni < 4; ++ni) {
        float p0 = pacc[ni][0] + bb.x;
        float p1 = pacc[ni][1] + bb.y;
        float p2 = pacc[ni][2] + bb.z;
        float p3 = pacc[ni][3] + bb.w;
        ushort4 pk;
        pk.x = f2bf(p0 > 0.f ? p0 : 0.f);
        pk.y = f2bf(p1 > 0.f ? p1 : 0.f);
        pk.z = f2bf(p2 > 0.f ? p2 : 0.f);
        pk.w = f2bf(p3 > 0.f ? p3 : 0.f);
        *(ushort4*)(smem + pw + ni * 4096) = pk;
      }
    }
    BAR_LGKM();   // single barrier per chunk: Psf[c&1] visible; prefetches in flight

    const unsigned short* pAn = w1b + (size_t)(c < 11 ? c + 1 : 11) * 49152;
    LDV(avB, pV, 1)
    __builtin_amdgcn_s_setprio(1); CMPV(avA, 0, pb) __builtin_amdgcn_s_setprio(0);
    LDV(avA, pV, 2)
    __builtin_amdgcn_s_setprio(1); CMPV(avB, 1, pb) __builtin_amdgcn_s_setprio(0);
    LDV(avB, pV, 3)
    __builtin_amdgcn_s_setprio(1); CMPV(avA, 2, pb) __builtin_amdgcn_s_setprio(0);
    LDA3(afA, pAn, 0)
    __builtin_amdgcn_s_setprio(1); CMPV(avB, 3, pb) __builtin_amdgcn_s_setprio(0);
    // no trailing barrier: next chunk writes Psf[(c+1)&1]
  }
  #undef LDV
  #undef CMPV

  // epilogue: out[row][ocol..+3] = oacc + b2 + res  (dwordx4)
  #pragma unroll
  for (int mi = 0; mi < 3; ++mi) {
    int ocb = w * 48 + mi * 16 + lq * 4;
    float4 b2v = *(const float4*)(b2 + ocb);
    #pragma unroll
    for (int ni = 0; ni < 4; ++ni) {
      size_t row = R0 + ni * 16 + l15;
      float* op = out + row * D_ + ocb;
      float4 r = *(const float4*)op;
      float4 o;
      o.x = oacc[mi][ni][0] + b2v.x + r.x;
      o.y = oacc[mi][ni][1] + b2v.y + r.y;
      o.z = oacc[mi][ni][2] + b2v.z + r.z;
      o.w = oacc[mi][ni][3] + b2v.w + r.w;
      *(float4*)op = o;
    }
  }
}

// ---------------- causal attention (+T5 setprio), one block per (b,h) ----------------
__global__ __launch_bounds__(256) void attn_kernel(const unsigned short* __restrict__ q,
                                                   const unsigned short* __restrict__ k,
                                                   const unsigned short* __restrict__ v,
                                                   unsigned short* __restrict__ o) {
  __shared__ __align__(16) char smem[52224];
  unsigned short (*Ks)[72]       = (unsigned short(*)[72])smem;
  unsigned short (*Ps)[32][136]  = (unsigned short(*)[32][136])smem;
  unsigned short (*Vt)[136]      = (unsigned short(*)[136])(smem + 34816);

  int bh = blockIdx.x;
  int b = bh / H_, h = bh % H_;
  int tid = threadIdx.x, w = tid >> 6, l = tid & 63;

  const unsigned short* kb = k + ((size_t)b * T_) * D_ + h * DH_;
  const unsigned short* vb = v + ((size_t)b * T_) * D_ + h * DH_;
  #pragma unroll
  for (int it = 0; it < 4; ++it) {
    int id = it * 256 + tid;
    int s = id >> 3, c8 = (id & 7) * 8;
    int4 kv = *(const int4*)(kb + (size_t)s * D_ + c8);
    *(int4*)(&Ks[s][c8]) = kv;
    int4 vv = *(const int4*)(vb + (size_t)s * D_ + c8);
    const unsigned short* pe = (const unsigned short*)&vv;
    #pragma unroll
    for (int j2 = 0; j2 < 8; ++j2) Vt[c8 + j2][s] = pe[j2];
  }
  __syncthreads();

  const unsigned short* qbp = q + ((size_t)b * T_) * D_ + h * DH_;
  int rowbase = w * 32;
  bf16x8 aq[2][2];
  #pragma unroll
  for (int mi = 0; mi < 2; ++mi)
    #pragma unroll
    for (int ks = 0; ks < 2; ++ks)
      aq[mi][ks] = *(const bf16x8*)(qbp + (size_t)(rowbase + mi*16 + (l & 15)) * D_
                                        + ks*32 + ((l >> 4) << 3));

  f32x4 accs[2][8];
  #pragma unroll
  for (int i = 0; i < 2; ++i)
    #pragma unroll
    for (int j = 0; j < 8; ++j) accs[i][j] = (f32x4){0.f, 0.f, 0.f, 0.f};
  #pragma unroll
  for (int ks = 0; ks < 2; ++ks) {
    bf16x8 bk[8];
    #pragma unroll
    for (int ni = 0; ni < 8; ++ni)
      bk[ni] = *(const bf16x8*)(&Ks[ni*16 + (l & 15)][ks*32 + ((l >> 4) << 3)]);
    __builtin_amdgcn_s_setprio(1);
    #pragma unroll
    for (int mi = 0; mi < 2; ++mi)
      #pragma unroll
      for (int ni = 0; ni < 8; ++ni)
        accs[mi][ni] = __builtin_amdgcn_mfma_f32_16x16x32_bf16(aq[mi][ks], bk[ni], accs[mi][ni], 0, 0, 0);
    __builtin_amdgcn_s_setprio(0);
  }
  __syncthreads();

  #pragma unroll
  for (int mi = 0; mi < 2; ++mi) {
    #pragma unroll
    for (int j = 0; j < 4; ++j) {
      int t = rowbase + mi*16 + ((l >> 4) << 2) + j;
      float mx = -1e30f;
      #pragma unroll
      for (int ni = 0; ni < 8; ++ni) {
        int scol = ni*16 + (l & 15);
        float sv = accs[mi][ni][j] * 0.125f;
        sv = (scol <= t) ? sv : -1e30f;
        accs[mi][ni][j] = sv;
        mx = fmaxf(mx, sv);
      }
      mx = fmaxf(mx, __shfl_xor(mx, 1));
      mx = fmaxf(mx, __shfl_xor(mx, 2));
      mx = fmaxf(mx, __shfl_xor(mx, 4));
      mx = fmaxf(mx, __shfl_xor(mx, 8));
      float sum = 0.f;
      #pragma unroll
      for (int ni = 0; ni < 8; ++ni) {
        float e = __expf(accs[mi][ni][j] - mx);
        accs[mi][ni][j] = e;
        sum += e;
      }
      sum += __shfl_xor(sum, 1);
      sum += __shfl_xor(sum, 2);
      sum += __shfl_xor(sum, 4);
      sum += __shfl_xor(sum, 8);
      float inv = 1.f / sum;
      #pragma unroll
      for (int ni = 0; ni < 8; ++ni)
        Ps[w][mi*16 + ((l >> 4) << 2) + j][ni*16 + (l & 15)] = f2bf(accs[mi][ni][j] * inv);
    }
  }
  __syncthreads();

  f32x4 acco[2][4];
  #pragma unroll
  for (int i = 0; i < 2; ++i)
    #pragma unroll
    for (int j = 0; j < 4; ++j) acco[i][j] = (f32x4){0.f, 0.f, 0.f, 0.f};
  #pragma unroll
  for (int ks = 0; ks < 4; ++ks) {
    bf16x8 ap[2], bv[4];
    #pragma unroll
    for (int mi = 0; mi < 2; ++mi)
      ap[mi] = *(const bf16x8*)(&Ps[w][mi*16 + (l & 15)][ks*32 + ((l >> 4) << 3)]);
    #pragma unroll
    for (int ni = 0; ni < 4; ++ni)
      bv[ni] = *(const bf16x8*)(&Vt[ni*16 + (l & 15)][ks*32 + ((l >> 4) << 3)]);
    __builtin_amdgcn_s_setprio(1);
    #pragma unroll
    for (int mi = 0; mi < 2; ++mi)
      #pragma unroll
      for (int ni = 0; ni < 4; ++ni)
        acco[mi][ni] = __builtin_amdgcn_mfma_f32_16x16x32_bf16(ap[mi], bv[ni], acco[mi][ni], 0, 0, 0);
    __builtin_amdgcn_s_setprio(0);
  }

  unsigned short* ob = o + ((size_t)b * T_) * D_ + h * DH_;
  #pragma unroll
  for (int mi = 0; mi < 2; ++mi)
    #pragma unroll
    for (int ni = 0; ni < 4; ++ni)
      #pragma unroll
      for (int j = 0; j < 4; ++j) {
        int t = rowbase + mi*16 + ((l >> 4) << 2) + j;
        int d = ni*16 + (l & 15);
        ob[(size_t)t * D_ + d] = f2bf(acco[mi][ni][j]);
      }
}

extern "C" void kernel_launch(void* const* d_in, const int* in_sizes, int n_in,
                              void* d_out, int out_size, void* d_ws, size_t ws_size,
                              hipStream_t stream) {
  const float* x   = (const float*)d_in[0];
  const float* Wq  = (const float*)d_in[1];
  const float* Wk  = (const float*)d_in[2];
  const float* Wv  = (const float*)d_in[3];
  const float* Wo  = (const float*)d_in[4];
  const float* bo  = (const float*)d_in[5];
  const float* W1  = (const float*)d_in[6];
  const float* b1  = (const float*)d_in[7];
  const float* W2  = (const float*)d_in[8];
  const float* b2  = (const float*)d_in[9];
  const float* g1  = (const float*)d_in[10];
  const float* be1 = (const float*)d_in[11];
  const float* g2  = (const float*)d_in[12];
  const float* be2 = (const float*)d_in[13];

  // workspace layout (bytes); total ~204 MiB
  char* ws = (char*)d_ws;
  unsigned short* hb    = (unsigned short*)(ws);               // h (LN1), later h2 (LN2)
  unsigned short* qb    = (unsigned short*)(ws +  50331648);   // q|k|v contiguous; o in-place
  unsigned short* kbuf  = (unsigned short*)(ws + 100663296);
  unsigned short* vbuf  = (unsigned short*)(ws + 150994944);
  unsigned short* wqkvP = (unsigned short*)(ws + 201326592);   // packed (NC=9)
  unsigned short* woP   = wqkvP + 442368;                      // packed (NC=3)
  unsigned short* w1P   = woP + 147456;                        // packed (NC=12)
  unsigned short* w2P   = w1P + 589824;                        // packed (w2)
  float* x2 = (float*)d_out;
  (void)kbuf; (void)vbuf;

  // allow 80KB dynamic LDS for ffn_fused (host-side attribute; idempotent)
  hipFuncSetAttribute(reinterpret_cast<const void*>(ffn_fused),
                      hipFuncAttributeMaxDynamicSharedMemorySize, 81920);

  // 1) unified fragment-order pack (one dispatch; bit-identical values)
  pack_all<<<dim3(864), 256, 0, stream>>>(Wq, Wk, Wv, Wo, W1, W2,
                                          wqkvP, woP, w1P, w2P);

  // 2) LN1 (grid-stride, math R9-exact): x -> h (bf16)
  ln_kernel<<<dim3(2048), 256, 0, stream>>>(x, g1, be1, hb);

  // 3) QKV GEMM v4 (64-row blocks): q|k|v = h @ [Wq|Wk|Wv]
  qkv_gemm<<<dim3(NROW / 64), 512, 0, stream>>>(hb, wqkvP, qb);

  // 4) attention: o overwrites q in place (per-block disjoint strips)
  attn_kernel<<<dim3(B_ * H_), 256, 0, stream>>>(qb, kbuf, vbuf, qb);

  // 5) fused Wo + residual + LN2: x2 -> d_out (fp32), h2 -> hb (bf16)
  wo_ln<<<dim3(NROW / 32), 512, 0, stream>>>(qb, woP, bo, x, g2, be2, x2, hb);

  // 6) fused FFN (dbuf-Psf, 1 barrier/chunk, 80KB dyn LDS; R22-exact)
  ffn_fused<<<dim3(NROW / 64), 512, 81920, stream>>>(hb, w1P, w2P, b1, b2, x2);
}

// Round 26
// 371.578 us; speedup vs baseline: 1.0339x; 1.0138x over previous
//
#include <hip/hip_runtime.h>

// Problem constants
#define B_   512
#define T_   128
#define D_   384
#define H_   6
#define DH_  64
#define DFF_ 1536
#define NROW (B_*T_)   // 65536 rows

typedef __attribute__((ext_vector_type(8))) short bf16x8;   // MFMA A/B frag (4 VGPRs)
typedef __attribute__((ext_vector_type(4))) float f32x4;    // MFMA C/D frag

__device__ __forceinline__ unsigned short f2bf(float f) {
  union { float f; unsigned u; } v; v.f = f;
  unsigned r = v.u + 0x7fffu + ((v.u >> 16) & 1u);   // RNE
  return (unsigned short)(r >> 16);
}

// lgkm-only barrier (keeps reg-destined global loads in flight)
#define BAR_LGKM() asm volatile("s_waitcnt lgkmcnt(0)\n\ts_barrier" ::: "memory")

// ======== prologue: unified weight pack + LN1, one dispatch =========================
// blocks [0,216): wqkv | [216,288): wo | [288,576): w1 | [576,864): w2
// blocks [864,2912): LN1 grid-stride (2048 blocks; math R9/R25-exact)
__global__ __launch_bounds__(256) void prologue_kernel(
    const float* __restrict__ Wq, const float* __restrict__ Wk,
    const float* __restrict__ Wv, const float* __restrict__ Wo,
    const float* __restrict__ W1, const float* __restrict__ W2,
    unsigned short* __restrict__ wqkvP, unsigned short* __restrict__ woP,
    unsigned short* __restrict__ w1P,   unsigned short* __restrict__ w2P,
    const float* __restrict__ x, const float* __restrict__ g,
    const float* __restrict__ be, unsigned short* __restrict__ hout) {
  int blk = blockIdx.x;
  if (blk < 216) {                                  // ---- wqkv (NC=9, K=384) ----
    int tid = blk * 256 + threadIdx.x;
    int lane = tid & 63, frag = tid >> 6;
    int k = frag % 12, t2 = frag / 12;
    int mi = t2 & 1, t3 = t2 >> 1;
    int w = t3 & 3, c = t3 >> 2;
    int l15 = lane & 15, lq = lane >> 4;
    int r = c * 128 + w * 32 + mi * 16 + l15;
    int col = k * 32 + lq * 8;
    const float* Wsrc = (c < 3) ? Wq : (c < 6) ? Wk : Wv;
    int rr = r - (c / 3) * 384;
    unsigned short tmp[8];
    #pragma unroll
    for (int e = 0; e < 8; ++e)
      tmp[e] = f2bf(Wsrc[(size_t)(col + e) * 384 + rr]);
    *(int4*)(wqkvP + (size_t)tid * 8) = *(const int4*)tmp;
  } else if (blk < 288) {                           // ---- wo (NC=3, K=384) ----
    int tid = (blk - 216) * 256 + threadIdx.x;
    int lane = tid & 63, frag = tid >> 6;
    int k = frag % 12, t2 = frag / 12;
    int mi = t2 & 1, t3 = t2 >> 1;
    int w = t3 & 3, c = t3 >> 2;
    int l15 = lane & 15, lq = lane >> 4;
    int r = c * 128 + w * 32 + mi * 16 + l15;
    int col = k * 32 + lq * 8;
    unsigned short tmp[8];
    #pragma unroll
    for (int e = 0; e < 8; ++e)
      tmp[e] = f2bf(Wo[(size_t)(col + e) * 384 + r]);
    *(int4*)(woP + (size_t)tid * 8) = *(const int4*)tmp;
  } else if (blk < 576) {                           // ---- w1 (NC=12, K=384, ld=1536) -
    int tid = (blk - 288) * 256 + threadIdx.x;
    int lane = tid & 63, frag = tid >> 6;
    int k = frag % 12, t2 = frag / 12;
    int mi = t2 & 1, t3 = t2 >> 1;
    int w = t3 & 3, c = t3 >> 2;
    int l15 = lane & 15, lq = lane >> 4;
    int r = c * 128 + w * 32 + mi * 16 + l15;
    int col = k * 32 + lq * 8;
    unsigned short tmp[8];
    #pragma unroll
    for (int e = 0; e < 8; ++e)
      tmp[e] = f2bf(W1[(size_t)(col + e) * 1536 + r]);
    *(int4*)(w1P + (size_t)tid * 8) = *(const int4*)tmp;
  } else if (blk < 864) {                           // ---- w2 (K=1536) ----
    int tid = (blk - 576) * 256 + threadIdx.x;
    int lane = tid & 63, frag = tid >> 6;
    int kk = frag & 3, t2 = frag >> 2;
    int c = t2 % 12, t3 = t2 / 12;
    int mi = t3 % 6, w = t3 / 6;
    int l15 = lane & 15, lq = lane >> 4;
    int r = w * 96 + mi * 16 + l15;
    int col = c * 128 + kk * 32 + lq * 8;
    unsigned short tmp[8];
    #pragma unroll
    for (int e = 0; e < 8; ++e)
      tmp[e] = f2bf(W2[(size_t)(col + e) * 384 + r]);
    *(int4*)(w2P + (size_t)tid * 8) = *(const int4*)tmp;
  } else {                                          // ---- LN1 grid-stride ----
    int l = threadIdx.x & 63;
    int wid0 = ((blk - 864) * 256 + threadIdx.x) >> 6;   // global wave id (2048 blks)
    int nw = 2048 * 4;
    for (int row = wid0; row < NROW; row += nw) {
      const float* xr = x + (size_t)row * D_;
      float v[6]; float s = 0.f, ss = 0.f;
      #pragma unroll
      for (int i = 0; i < 6; ++i) { v[i] = xr[l + i*64]; s += v[i]; ss += v[i]*v[i]; }
      #pragma unroll
      for (int m = 1; m < 64; m <<= 1) { s += __shfl_xor(s, m); ss += __shfl_xor(ss, m); }
      float mu  = s * (1.f / D_);
      float var = ss * (1.f / D_) - mu * mu;
      float rs  = rsqrtf(var + 1e-5f);
      unsigned short* orow = hout + (size_t)row * D_;
      #pragma unroll
      for (int i = 0; i < 6; ++i) {
        int c = l + i*64;
        orow[c] = f2bf((v[i] - mu) * rs * g[c] + be[c]);
      }
    }
  }
}

// ---------------- QKV GEMM v4 (64-row block, k-outer, deferred epilogue; R22) -------
__global__ __launch_bounds__(512, 2) void qkv_gemm(
    const unsigned short* __restrict__ h, const unsigned short* __restrict__ wP,
    unsigned short* __restrict__ qkv)
{
  __shared__ __align__(16) char smem[49152];   // staging 48KB | epilogue 32x784 reuse
  int tid = threadIdx.x, w = tid >> 6, l = tid & 63;
  int l15 = l & 15, lq = l >> 4;
  size_t R0 = (size_t)blockIdx.x * 64;

  // ---- stage h strip (64 rows) -> frag-order LDS (ffn-proven 512thr x 6 int4) ----
  {
    int row = tid >> 3, gi = row >> 4, l15w = row & 15;
    int cbase = (tid & 7) * 48;
    const unsigned short* src = h + (R0 + row) * 384 + cbase;
    #pragma unroll
    for (int i = 0; i < 6; ++i) {
      int col = cbase + i * 8;
      int k = col >> 5, lqw = (col >> 3) & 3;
      *(int4*)(smem + (gi*12 + k)*1024 + (lqw*16 + l15w)*16) = *(const int4*)(src + i*8);
    }
  }
  __syncthreads();

  f32x4 acc[9][4];
  #pragma unroll
  for (int c = 0; c < 9; ++c)
    #pragma unroll
    for (int ni = 0; ni < 4; ++ni) acc[c][ni] = (f32x4){0.f, 0.f, 0.f, 0.f};

  const unsigned short* wb = wP + l * 8;       // + ((c*8+w)*12 + k)*512

  #define LDG(dst, cb, k)                                                    \
    { _Pragma("unroll") for (int ci = 0; ci < 3; ++ci)                       \
        dst[ci] = *(const bf16x8*)(wb + (((cb)+ci)*8 + w) * 6144 + (k) * 512); }

  #define CMPG(buf, cb)                                                      \
    { _Pragma("unroll") for (int ci = 0; ci < 3; ++ci)                       \
        _Pragma("unroll") for (int ni = 0; ni < 4; ++ni)                     \
          acc[(cb)+ci][ni] = __builtin_amdgcn_mfma_f32_16x16x32_bf16(        \
              buf[ci], bfr[ni], acc[(cb)+ci][ni], 0, 0, 0); }

  bf16x8 a0[3], a1[3], a2[3];
  LDG(a0, 0, 0)                                // preload k=0 group 0

  for (int k = 0; k < 12; ++k) {
    bf16x8 bfr[4];
    #pragma unroll
    for (int ni = 0; ni < 4; ++ni)
      bfr[ni] = *(const bf16x8*)(smem + (ni*12 + k)*1024 + l*16);
    int kn = (k < 11) ? k + 1 : 11;
    LDG(a1, 3, k)
    __builtin_amdgcn_s_setprio(1); CMPG(a0, 0) __builtin_amdgcn_s_setprio(0);
    LDG(a2, 6, k)
    __builtin_amdgcn_s_setprio(1); CMPG(a1, 3) __builtin_amdgcn_s_setprio(0);
    LDG(a0, 0, kn)
    __builtin_amdgcn_s_setprio(1); CMPG(a2, 6) __builtin_amdgcn_s_setprio(0);
  }
  #undef LDG
  #undef CMPG

  // ---- deferred epilogue: per buffer x per 32-row half: acc -> LDS -> int4 stores
  __syncthreads();                              // staging region dead; reads drained
  #pragma unroll
  for (int buf = 0; buf < 3; ++buf) {
    #pragma unroll
    for (int half = 0; half < 2; ++half) {
      #pragma unroll
      for (int ci = 0; ci < 3; ++ci) {
        int c = buf * 3 + ci;
        #pragma unroll
        for (int n2 = 0; n2 < 2; ++n2) {
          int ni = half * 2 + n2;
          int lrow = n2 * 16 + l15;
          ushort4 pk;
          pk.x = f2bf(acc[c][ni][0]);
          pk.y = f2bf(acc[c][ni][1]);
          pk.z = f2bf(acc[c][ni][2]);
          pk.w = f2bf(acc[c][ni][3]);
          *(ushort4*)(smem + lrow * 784 + ci * 256 + w * 32 + lq * 8) = pk;
        }
      }
      __syncthreads();
      {
        int row = tid >> 4;
        unsigned short* obase = qkv + (size_t)buf * NROW * 384
                              + (R0 + half * 32 + row) * 384;
        #pragma unroll
        for (int i = 0; i < 3; ++i) {
          int ob = (tid & 15) * 16 + i * 256;   // byte offset in 768-B row
          *(int4*)(obase + (ob >> 1)) = *(const int4*)(smem + row * 784 + ob);
        }
      }
      __syncthreads();
    }
  }
}

// ---------------- fused Wo + residual + LN2 (32-row block; R19-proven) --------------
__global__ __launch_bounds__(512, 4) void wo_ln(
    const unsigned short* __restrict__ o,    // [NROW][384] bf16 (attention out)
    const unsigned short* __restrict__ wP,   // woP packed (NC=3)
    const float* __restrict__ bo, const float* __restrict__ xres,
    const float* __restrict__ g, const float* __restrict__ be,
    float* __restrict__ x2out,               // d_out
    unsigned short* __restrict__ h2out)      // hb
{
  __shared__ __align__(16) char smem[50176]; // staging 24576 (reused) | x2 tile 32x392 f32
  int tid = threadIdx.x, w = tid >> 6, l = tid & 63;
  int l15 = l & 15, lq = l >> 4;
  size_t R0 = (size_t)blockIdx.x * 32;

  // ---- stage o strip (32 rows) -> frag-order LDS (qkv-v3 pattern) ----
  {
    int row = tid >> 4, gi = row >> 4, l15w = row & 15;
    const unsigned short* src = o + (R0 + row) * 384 + (tid & 15) * 24;
    #pragma unroll
    for (int i = 0; i < 3; ++i) {
      int col = (tid & 15) * 24 + i * 8;
      int k = col >> 5, lqw = (col >> 3) & 3;
      *(int4*)(smem + (gi*12 + k)*1024 + (lqw*16 + l15w)*16) = *(const int4*)(src + i*8);
    }
  }
  __syncthreads();

  f32x4 acc[3][2];
  #pragma unroll
  for (int c = 0; c < 3; ++c)
    #pragma unroll
    for (int ni = 0; ni < 2; ++ni) acc[c][ni] = (f32x4){0.f, 0.f, 0.f, 0.f};

  const unsigned short* wb = wP + l * 8;       // + ((ci*8+w)*12 + k)*512

  #define LDGW(dst, k)                                                       \
    { _Pragma("unroll") for (int ci = 0; ci < 3; ++ci)                       \
        dst[ci] = *(const bf16x8*)(wb + (ci*8 + w) * 6144 + (k) * 512); }

  #define CMPW(buf)                                                          \
    { _Pragma("unroll") for (int ci = 0; ci < 3; ++ci)                       \
        _Pragma("unroll") for (int ni = 0; ni < 2; ++ni)                     \
          acc[ci][ni] = __builtin_amdgcn_mfma_f32_16x16x32_bf16(             \
              buf[ci], bfr[ni], acc[ci][ni], 0, 0, 0); }

  bf16x8 aA[3], aB[3];
  LDGW(aA, 0)
  for (int k = 0; k < 12; k += 2) {
    bf16x8 bfr[2];
    #pragma unroll
    for (int ni = 0; ni < 2; ++ni)
      bfr[ni] = *(const bf16x8*)(smem + (ni*12 + k)*1024 + l*16);
    LDGW(aB, k + 1)
    __builtin_amdgcn_s_setprio(1); CMPW(aA) __builtin_amdgcn_s_setprio(0);
    #pragma unroll
    for (int ni = 0; ni < 2; ++ni)
      bfr[ni] = *(const bf16x8*)(smem + (ni*12 + k + 1)*1024 + l*16);
    int kn = (k + 2 < 12) ? k + 2 : 11;
    LDGW(aA, kn)
    __builtin_amdgcn_s_setprio(1); CMPW(aB) __builtin_amdgcn_s_setprio(0);
  }
  #undef LDGW
  #undef CMPW

  // ---- epilogue: x2 = acc + bo + x -> LDS tile [32][392] f32 ----
  __syncthreads();                              // staging reads retired
  #pragma unroll
  for (int ci = 0; ci < 3; ++ci) {
    int col = ci * 128 + w * 16 + lq * 4;
    float4 bb = *(const float4*)(bo + col);
    #pragma unroll
    for (int ni = 0; ni < 2; ++ni) {
      int row = ni * 16 + l15;
      float4 r = *(const float4*)(xres + (R0 + row) * 384 + col);
      float4 v;
      v.x = acc[ci][ni][0] + bb.x + r.x;
      v.y = acc[ci][ni][1] + bb.y + r.y;
      v.z = acc[ci][ni][2] + bb.z + r.z;
      v.w = acc[ci][ni][3] + bb.w + r.w;
      *(float4*)(smem + row * 1568 + col * 4) = v;
    }
  }
  __syncthreads();

  // ---- LN2 on the tile: 16 thr/row; emit x2 fp32 + h2 bf16 (coalesced) ----
  {
    int row = tid >> 4, t16 = tid & 15;
    const char* rbase = smem + row * 1568;
    float4 vv[6];
    float s = 0.f, ss = 0.f;
    #pragma unroll
    for (int i = 0; i < 6; ++i) {
      vv[i] = *(const float4*)(rbase + (t16 + i * 16) * 16);
      s  += vv[i].x + vv[i].y + vv[i].z + vv[i].w;
      ss += vv[i].x*vv[i].x + vv[i].y*vv[i].y + vv[i].z*vv[i].z + vv[i].w*vv[i].w;
    }
    s += __shfl_xor(s, 1); ss += __shfl_xor(ss, 1);
    s += __shfl_xor(s, 2); ss += __shfl_xor(ss, 2);
    s += __shfl_xor(s, 4); ss += __shfl_xor(ss, 4);
    s += __shfl_xor(s, 8); ss += __shfl_xor(ss, 8);
    float mu = s * (1.f / 384.f);
    float rs = rsqrtf(ss * (1.f / 384.f) - mu * mu + 1e-5f);
    float* xrow = x2out + (R0 + row) * 384;
    unsigned short* hrow = h2out + (R0 + row) * 384;
    #pragma unroll
    for (int i = 0; i < 6; ++i) {
      int c4 = t16 + i * 16;                   // float4 index in row
      float4 ga = *(const float4*)(g  + c4 * 4);
      float4 ba = *(const float4*)(be + c4 * 4);
      *(float4*)(xrow + c4 * 4) = vv[i];
      ushort4 pk;
      pk.x = f2bf((vv[i].x - mu) * rs * ga.x + ba.x);
      pk.y = f2bf((vv[i].y - mu) * rs * ga.y + ba.y);
      pk.z = f2bf((vv[i].z - mu) * rs * ga.z + ba.z);
      pk.w = f2bf((vv[i].w - mu) * rs * ga.w + ba.w);
      *(ushort4*)(hrow + c4 * 4) = pk;
    }
  }
}

// ======== 8-wave ffn building blocks (frag-order LDS + packed W) ========
#define LDA3(dst, pA, k0)                                                    \
  { _Pragma("unroll") for (int kq = 0; kq < 3; ++kq)                         \
      dst[kq] = *(const bf16x8*)((pA) + ((k0) + kq) * 512); }

#define CMP3(buf, k0, acc)                                                   \
  { _Pragma("unroll") for (int kq = 0; kq < 3; ++kq) {                       \
      bf16x8 bfr[4];                                                         \
      _Pragma("unroll") for (int ni = 0; ni < 4; ++ni)                       \
        bfr[ni] = *(const bf16x8*)(smem + (ni*12 + (k0)+kq)*1024 + l*16);    \
      _Pragma("unroll") for (int ni = 0; ni < 4; ++ni)                       \
        acc[ni] = __builtin_amdgcn_mfma_f32_16x16x32_bf16(                   \
            buf[kq], bfr[ni], acc[ni], 0, 0, 0);                             \
    } }

// ---------------- fused FFN (8-wave, setprio, dbuf Psf, 1 barrier/chunk; R22-exact) -
__global__ __launch_bounds__(512, 4) void ffn_fused(
    const unsigned short* __restrict__ h2,   // [NROW][384] bf16
    const unsigned short* __restrict__ w1P,  // packed (NC=12)
    const unsigned short* __restrict__ w2P,  // packed (w2)
    const float* __restrict__ b1,            // [1536]
    const float* __restrict__ b2,            // [384]
    float* __restrict__ out)                 // [NROW][384] fp32, in-place residual add
{
  extern __shared__ __align__(16) char smem[];
  int tid = threadIdx.x, w = tid >> 6, l = tid & 63;
  int l15 = l & 15, lq = l >> 4;
  size_t R0 = (size_t)blockIdx.x * 64;

  // ---- stage h2 strip -> frag-order LDS (512 thr x 48 elems) ----
  {
    int row = tid >> 3, gi = row >> 4, l15w = row & 15;
    int cbase = (tid & 7) * 48;
    const unsigned short* src = h2 + (R0 + row) * 384 + cbase;
    #pragma unroll
    for (int i = 0; i < 6; ++i) {
      int col = cbase + i * 8;
      int k = col >> 5, lqw = (col >> 3) & 3;
      *(int4*)(smem + (gi*12 + k)*1024 + (lqw*16 + l15w)*16) = *(const int4*)(src + i*8);
    }
  }
  __syncthreads();

  f32x4 oacc[3][4];
  #pragma unroll
  for (int i = 0; i < 3; ++i)
    #pragma unroll
    for (int j = 0; j < 4; ++j) oacc[i][j] = (f32x4){0.f, 0.f, 0.f, 0.f};

  const unsigned short* w1b = w1P + w * 6144  + l * 8;  // + c*49152 + k*512
  const unsigned short* w2b = w2P + w * 73728 + l * 8;  // + mi*24576 + c*2048 + kk*512

  #define LDV(dst, pV, kk)                                                   \
    { _Pragma("unroll") for (int mi = 0; mi < 3; ++mi)                       \
        dst[mi] = *(const bf16x8*)((pV) + mi * 24576 + (kk) * 512); }

  #define CMPV(buf, kk, pb)                                                  \
    { bf16x8 bv[4];                                                          \
      _Pragma("unroll") for (int ni = 0; ni < 4; ++ni)                       \
        bv[ni] = *(const bf16x8*)(smem + (pb) + (ni*4 + (kk))*1024 + l*16);  \
      _Pragma("unroll") for (int mi = 0; mi < 3; ++mi)                       \
        _Pragma("unroll") for (int ni = 0; ni < 4; ++ni)                     \
          oacc[mi][ni] = __builtin_amdgcn_mfma_f32_16x16x32_bf16(            \
              buf[mi], bv[ni], oacc[mi][ni], 0, 0, 0);                       \
    }

  bf16x8 afA[3], afB[3];
  bf16x8 avA[3], avB[3];

  LDA3(afA, w1b, 0)   // prologue: first P-group of chunk 0

  for (int c = 0; c < 12; ++c) {
    const unsigned short* pA = w1b + (size_t)c * 49152;
    const unsigned short* pV = w2b + c * 2048;
    unsigned pb = 49152u + (unsigned)(c & 1) * 16384u;

    f32x4 pacc[4];
    #pragma unroll
    for (int j = 0; j < 4; ++j) pacc[j] = (f32x4){0.f, 0.f, 0.f, 0.f};

    // P-phase: 4 groups of 3 k-steps, ping-pong prefetch; T5 around MFMA clusters
    LDA3(afB, pA, 3)
    __builtin_amdgcn_s_setprio(1); CMP3(afA, 0, pacc) __builtin_amdgcn_s_setprio(0);
    LDA3(afA, pA, 6)
    __builtin_amdgcn_s_setprio(1); CMP3(afB, 3, pacc) __builtin_amdgcn_s_setprio(0);
    LDA3(afB, pA, 9)
    __builtin_amdgcn_s_setprio(1); CMP3(afA, 6, pacc) __builtin_amdgcn_s_setprio(0);
    LDV(avA, pV, 0)
    __builtin_amdgcn_s_setprio(1); CMP3(afB, 9, pacc) __builtin_amdgcn_s_setprio(0);

    // P epilogue: bias1 + relu + bf16 pack -> Psf[c&1]
    {
      int fcb = c * 128 + w * 16 + lq * 4;
      float4 bb = *(const float4*)(b1 + fcb);
      unsigned pw = pb + (unsigned)((w >> 1) * 1024 +
                    (((w & 1) * 2 + (lq >> 1)) * 16 + l15) * 16 + (lq & 1) * 8);
      #pragma unroll
      for (int ni = 0; ni < 4; ++ni) {
        float p0 = pacc[ni][0] + bb.x;
        float p1 = pacc[ni][1] + bb.y;
        float p2 = pacc[ni][2] + bb.z;
        float p3 = pacc[ni][3] + bb.w;
        ushort4 pk;
        pk.x = f2bf(p0 > 0.f ? p0 : 0.f);
        pk.y = f2bf(p1 > 0.f ? p1 : 0.f);
        pk.z = f2bf(p2 > 0.f ? p2 : 0.f);
        pk.w = f2bf(p3 > 0.f ? p3 : 0.f);
        *(ushort4*)(smem + pw + ni * 4096) = pk;
      }
    }
    BAR_LGKM();   // single barrier per chunk: Psf[c&1] visible; prefetches in flight

    const unsigned short* pAn = w1b + (size_t)(c < 11 ? c + 1 : 11) * 49152;
    LDV(avB, pV, 1)
    __builtin_amdgcn_s_setprio(1); CMPV(avA, 0, pb) __builtin_amdgcn_s_setprio(0);
    LDV(avA, pV, 2)
    __builtin_amdgcn_s_setprio(1); CMPV(avB, 1, pb) __builtin_amdgcn_s_setprio(0);
    LDV(avB, pV, 3)
    __builtin_amdgcn_s_setprio(1); CMPV(avA, 2, pb) __builtin_amdgcn_s_setprio(0);
    LDA3(afA, pAn, 0)
    __builtin_amdgcn_s_setprio(1); CMPV(avB, 3, pb) __builtin_amdgcn_s_setprio(0);
    // no trailing barrier: next chunk writes Psf[(c+1)&1]
  }
  #undef LDV
  #undef CMPV

  // epilogue: out[row][ocol..+3] = oacc + b2 + res  (dwordx4)
  #pragma unroll
  for (int mi = 0; mi < 3; ++mi) {
    int ocb = w * 48 + mi * 16 + lq * 4;
    float4 b2v = *(const float4*)(b2 + ocb);
    #pragma unroll
    for (int ni = 0; ni < 4; ++ni) {
      size_t row = R0 + ni * 16 + l15;
      float* op = out + row * D_ + ocb;
      float4 r = *(const float4*)op;
      float4 o;
      o.x = oacc[mi][ni][0] + b2v.x + r.x;
      o.y = oacc[mi][ni][1] + b2v.y + r.y;
      o.z = oacc[mi][ni][2] + b2v.z + r.z;
      o.w = oacc[mi][ni][3] + b2v.w + r.w;
      *(float4*)op = o;
    }
  }
}

// ---------------- causal attention (+T5 setprio), one block per (b,h) ----------------
__global__ __launch_bounds__(256) void attn_kernel(const unsigned short* __restrict__ q,
                                                   const unsigned short* __restrict__ k,
                                                   const unsigned short* __restrict__ v,
                                                   unsigned short* __restrict__ o) {
  __shared__ __align__(16) char smem[52224];
  unsigned short (*Ks)[72]       = (unsigned short(*)[72])smem;
  unsigned short (*Ps)[32][136]  = (unsigned short(*)[32][136])smem;
  unsigned short (*Vt)[136]      = (unsigned short(*)[136])(smem + 34816);

  int bh = blockIdx.x;
  int b = bh / H_, h = bh % H_;
  int tid = threadIdx.x, w = tid >> 6, l = tid & 63;

  const unsigned short* kb = k + ((size_t)b * T_) * D_ + h * DH_;
  const unsigned short* vb = v + ((size_t)b * T_) * D_ + h * DH_;
  #pragma unroll
  for (int it = 0; it < 4; ++it) {
    int id = it * 256 + tid;
    int s = id >> 3, c8 = (id & 7) * 8;
    int4 kv = *(const int4*)(kb + (size_t)s * D_ + c8);
    *(int4*)(&Ks[s][c8]) = kv;
    int4 vv = *(const int4*)(vb + (size_t)s * D_ + c8);
    const unsigned short* pe = (const unsigned short*)&vv;
    #pragma unroll
    for (int j2 = 0; j2 < 8; ++j2) Vt[c8 + j2][s] = pe[j2];
  }
  __syncthreads();

  const unsigned short* qbp = q + ((size_t)b * T_) * D_ + h * DH_;
  int rowbase = w * 32;
  bf16x8 aq[2][2];
  #pragma unroll
  for (int mi = 0; mi < 2; ++mi)
    #pragma unroll
    for (int ks = 0; ks < 2; ++ks)
      aq[mi][ks] = *(const bf16x8*)(qbp + (size_t)(rowbase + mi*16 + (l & 15)) * D_
                                        + ks*32 + ((l >> 4) << 3));

  f32x4 accs[2][8];
  #pragma unroll
  for (int i = 0; i < 2; ++i)
    #pragma unroll
    for (int j = 0; j < 8; ++j) accs[i][j] = (f32x4){0.f, 0.f, 0.f, 0.f};
  #pragma unroll
  for (int ks = 0; ks < 2; ++ks) {
    bf16x8 bk[8];
    #pragma unroll
    for (int ni = 0; ni < 8; ++ni)
      bk[ni] = *(const bf16x8*)(&Ks[ni*16 + (l & 15)][ks*32 + ((l >> 4) << 3)]);
    __builtin_amdgcn_s_setprio(1);
    #pragma unroll
    for (int mi = 0; mi < 2; ++mi)
      #pragma unroll
      for (int ni = 0; ni < 8; ++ni)
        accs[mi][ni] = __builtin_amdgcn_mfma_f32_16x16x32_bf16(aq[mi][ks], bk[ni], accs[mi][ni], 0, 0, 0);
    __builtin_amdgcn_s_setprio(0);
  }
  __syncthreads();

  #pragma unroll
  for (int mi = 0; mi < 2; ++mi) {
    #pragma unroll
    for (int j = 0; j < 4; ++j) {
      int t = rowbase + mi*16 + ((l >> 4) << 2) + j;
      float mx = -1e30f;
      #pragma unroll
      for (int ni = 0; ni < 8; ++ni) {
        int scol = ni*16 + (l & 15);
        float sv = accs[mi][ni][j] * 0.125f;
        sv = (scol <= t) ? sv : -1e30f;
        accs[mi][ni][j] = sv;
        mx = fmaxf(mx, sv);
      }
      mx = fmaxf(mx, __shfl_xor(mx, 1));
      mx = fmaxf(mx, __shfl_xor(mx, 2));
      mx = fmaxf(mx, __shfl_xor(mx, 4));
      mx = fmaxf(mx, __shfl_xor(mx, 8));
      float sum = 0.f;
      #pragma unroll
      for (int ni = 0; ni < 8; ++ni) {
        float e = __expf(accs[mi][ni][j] - mx);
        accs[mi][ni][j] = e;
        sum += e;
      }
      sum += __shfl_xor(sum, 1);
      sum += __shfl_xor(sum, 2);
      sum += __shfl_xor(sum, 4);
      sum += __shfl_xor(sum, 8);
      float inv = 1.f / sum;
      #pragma unroll
      for (int ni = 0; ni < 8; ++ni)
        Ps[w][mi*16 + ((l >> 4) << 2) + j][ni*16 + (l & 15)] = f2bf(accs[mi][ni][j] * inv);
    }
  }
  __syncthreads();

  f32x4 acco[2][4];
  #pragma unroll
  for (int i = 0; i < 2; ++i)
    #pragma unroll
    for (int j = 0; j < 4; ++j) acco[i][j] = (f32x4){0.f, 0.f, 0.f, 0.f};
  #pragma unroll
  for (int ks = 0; ks < 4; ++ks) {
    bf16x8 ap[2], bv[4];
    #pragma unroll
    for (int mi = 0; mi < 2; ++mi)
      ap[mi] = *(const bf16x8*)(&Ps[w][mi*16 + (l & 15)][ks*32 + ((l >> 4) << 3)]);
    #pragma unroll
    for (int ni = 0; ni < 4; ++ni)
      bv[ni] = *(const bf16x8*)(&Vt[ni*16 + (l & 15)][ks*32 + ((l >> 4) << 3)]);
    __builtin_amdgcn_s_setprio(1);
    #pragma unroll
    for (int mi = 0; mi < 2; ++mi)
      #pragma unroll
      for (int ni = 0; ni < 4; ++ni)
        acco[mi][ni] = __builtin_amdgcn_mfma_f32_16x16x32_bf16(ap[mi], bv[ni], acco[mi][ni], 0, 0, 0);
    __builtin_amdgcn_s_setprio(0);
  }

  unsigned short* ob = o + ((size_t)b * T_) * D_ + h * DH_;
  #pragma unroll
  for (int mi = 0; mi < 2; ++mi)
    #pragma unroll
    for (int ni = 0; ni < 4; ++ni)
      #pragma unroll
      for (int j = 0; j < 4; ++j) {
        int t = rowbase + mi*16 + ((l >> 4) << 2) + j;
        int d = ni*16 + (l & 15);
        ob[(size_t)t * D_ + d] = f2bf(acco[mi][ni][j]);
      }
}

extern "C" void kernel_launch(void* const* d_in, const int* in_sizes, int n_in,
                              void* d_out, int out_size, void* d_ws, size_t ws_size,
                              hipStream_t stream) {
  const float* x   = (const float*)d_in[0];
  const float* Wq  = (const float*)d_in[1];
  const float* Wk  = (const float*)d_in[2];
  const float* Wv  = (const float*)d_in[3];
  const float* Wo  = (const float*)d_in[4];
  const float* bo  = (const float*)d_in[5];
  const float* W1  = (const float*)d_in[6];
  const float* b1  = (const float*)d_in[7];
  const float* W2  = (const float*)d_in[8];
  const float* b2  = (const float*)d_in[9];
  const float* g1  = (const float*)d_in[10];
  const float* be1 = (const float*)d_in[11];
  const float* g2  = (const float*)d_in[12];
  const float* be2 = (const float*)d_in[13];

  // workspace layout (bytes); total ~204 MiB
  char* ws = (char*)d_ws;
  unsigned short* hb    = (unsigned short*)(ws);               // h (LN1), later h2 (LN2)
  unsigned short* qb    = (unsigned short*)(ws +  50331648);   // q|k|v contiguous; o in-place
  unsigned short* kbuf  = (unsigned short*)(ws + 100663296);
  unsigned short* vbuf  = (unsigned short*)(ws + 150994944);
  unsigned short* wqkvP = (unsigned short*)(ws + 201326592);   // packed (NC=9)
  unsigned short* woP   = wqkvP + 442368;                      // packed (NC=3)
  unsigned short* w1P   = woP + 147456;                        // packed (NC=12)
  unsigned short* w2P   = w1P + 589824;                        // packed (w2)
  float* x2 = (float*)d_out;
  (void)kbuf; (void)vbuf;

  // allow 80KB dynamic LDS for ffn_fused (host-side attribute; idempotent)
  hipFuncSetAttribute(reinterpret_cast<const void*>(ffn_fused),
                      hipFuncAttributeMaxDynamicSharedMemorySize, 81920);

  // 1) prologue: weight packs + LN1 overlapped in one dispatch (both bit-identical)
  prologue_kernel<<<dim3(2912), 256, 0, stream>>>(Wq, Wk, Wv, Wo, W1, W2,
                                                  wqkvP, woP, w1P, w2P,
                                                  x, g1, be1, hb);

  // 2) QKV GEMM v4 (64-row blocks): q|k|v = h @ [Wq|Wk|Wv]
  qkv_gemm<<<dim3(NROW / 64), 512, 0, stream>>>(hb, wqkvP, qb);

  // 3) attention: o overwrites q in place (per-block disjoint strips)
  attn_kernel<<<dim3(B_ * H_), 256, 0, stream>>>(qb, kbuf, vbuf, qb);

  // 4) fused Wo + residual + LN2: x2 -> d_out (fp32), h2 -> hb (bf16)
  wo_ln<<<dim3(NROW / 32), 512, 0, stream>>>(qb, woP, bo, x, g2, be2, x2, hb);

  // 5) fused FFN (dbuf-Psf, 1 barrier/chunk, 80KB dyn LDS; R22-exact)
  ffn_fused<<<dim3(NROW / 64), 512, 81920, stream>>>(hb, w1P, w2P, b1, b2, x2);
}